// Round 3
// baseline (590.534 us; speedup 1.0000x reference)
//
#include <hip/hip_runtime.h>
#include <hip/hip_bf16.h>
#include <stdint.h>

typedef unsigned short u16;
typedef __attribute__((ext_vector_type(8))) short bf16x8;
typedef __attribute__((ext_vector_type(4))) float f32x4;

#define DI __device__ __forceinline__

DI float b2f(u16 u) { return __uint_as_float(((uint32_t)u) << 16); }
DI u16 f2b(float f) {
  uint32_t u = __float_as_uint(f);
  u += 0x7fff + ((u >> 16) & 1);   // RNE
  return (u16)(u >> 16);
}

// ---------------------------------------------------------------------------
// Convert 8 weight matrices (512x512 f32) to bf16, concatenated at dst.
// Grid: 1024 blocks x 256 threads, 8 elements/thread.
// ---------------------------------------------------------------------------
__global__ __launch_bounds__(256)
void convert_w8(const float* __restrict__ w0, const float* __restrict__ w1,
                const float* __restrict__ w2, const float* __restrict__ w3,
                const float* __restrict__ w4, const float* __restrict__ w5,
                const float* __restrict__ w6, const float* __restrict__ w7,
                u16* __restrict__ dst)
{
  const float* srcs[8] = {w0, w1, w2, w3, w4, w5, w6, w7};
  const int mat = blockIdx.x >> 7;                 // 128 blocks per matrix
  const int i = (((blockIdx.x & 127) << 8) + threadIdx.x) * 8;
  const float* s = srcs[mat];
  float4 a = *(const float4*)(s + i);
  float4 b = *(const float4*)(s + i + 4);
  alignas(16) u16 v[8] = {f2b(a.x), f2b(a.y), f2b(a.z), f2b(a.w),
                          f2b(b.x), f2b(b.y), f2b(b.z), f2b(b.w)};
  *(uint4*)(dst + (long)mat * 262144 + i) = *(const uint4*)v;
}

// ---------------------------------------------------------------------------
// Batched GEMM: out[m][n] = alpha * sum_k A[m][k]*Bt[n][k]  (+bias, +resid)
// A,Bt bf16; bias/resid f32; out bf16 or f32 (OUTF32).
// BM=BN=128, BK=32, 256 threads (4 waves as 2x2 of 64x64), 16x16x32 bf16 MFMA.
// BIASMODE: 0 none, 1 bias[row], 2 bias[col].
// ---------------------------------------------------------------------------
template<int OUTF32, int BIASMODE, int RESID>
__global__ __launch_bounds__(256)
void gemm_bt(const u16* __restrict__ A, long sA,
             const u16* __restrict__ B, long sB,
             void* __restrict__ C, long sC,
             const float* __restrict__ bias,
             const float* __restrict__ resid, long sR,
             int N, int K, float alpha)
{
  __shared__ u16 lA[128 * 32];
  __shared__ u16 lB[128 * 32];
  const int t = threadIdx.x;
  const int lane = t & 63;
  const int m0 = blockIdx.y * 128, n0 = blockIdx.x * 128;
  const long bz = blockIdx.z;
  const u16* Ab = A + bz * sA;
  const u16* Bb = B + bz * sB;

  const int row = t >> 2;          // 0..63
  const int kc  = (t & 3) * 8;     // k-element offset of this thread's 16B chunk

  f32x4 acc[4][4];
#pragma unroll
  for (int i = 0; i < 4; ++i)
#pragma unroll
    for (int j = 0; j < 4; ++j) acc[i][j] = (f32x4){0.f, 0.f, 0.f, 0.f};

  const int wid = t >> 6;
  const int ml = lane & 15, qd = lane >> 4;
  const int wm = (wid >> 1) * 64, wn = (wid & 1) * 64;

  for (int k0 = 0; k0 < K; k0 += 32) {
    uint4 a0 = *(const uint4*)(Ab + (long)(m0 + row) * K + (k0 + kc));
    uint4 a1 = *(const uint4*)(Ab + (long)(m0 + 64 + row) * K + (k0 + kc));
    uint4 b0 = *(const uint4*)(Bb + (long)(n0 + row) * K + (k0 + kc));
    uint4 b1 = *(const uint4*)(Bb + (long)(n0 + 64 + row) * K + (k0 + kc));
    *(uint4*)&lA[row * 32 + kc]        = a0;
    *(uint4*)&lA[(64 + row) * 32 + kc] = a1;
    *(uint4*)&lB[row * 32 + kc]        = b0;
    *(uint4*)&lB[(64 + row) * 32 + kc] = b1;
    __syncthreads();
    bf16x8 af[4], bfr[4];
#pragma unroll
    for (int i = 0; i < 4; ++i)
      af[i] = *(const bf16x8*)&lA[(wm + i * 16 + ml) * 32 + qd * 8];
#pragma unroll
    for (int j = 0; j < 4; ++j)
      bfr[j] = *(const bf16x8*)&lB[(wn + j * 16 + ml) * 32 + qd * 8];
#pragma unroll
    for (int i = 0; i < 4; ++i)
#pragma unroll
      for (int j = 0; j < 4; ++j)
        acc[i][j] = __builtin_amdgcn_mfma_f32_16x16x32_bf16(af[i], bfr[j], acc[i][j], 0, 0, 0);
    __syncthreads();
  }

  const long cb = bz * sC;
#pragma unroll
  for (int i = 0; i < 4; ++i) {
#pragma unroll
    for (int j = 0; j < 4; ++j) {
#pragma unroll
      for (int r = 0; r < 4; ++r) {
        int rr = m0 + wm + i * 16 + qd * 4 + r;   // C/D row = quad*4+reg (m89)
        int cc = n0 + wn + j * 16 + ml;           // C/D col = lane&15
        float v = acc[i][j][r] * alpha;
        if (BIASMODE == 1) v += bias[rr];
        if (BIASMODE == 2) v += bias[cc];
        long idx = (long)rr * N + cc;
        if (RESID) v += resid[bz * sR + idx];
        if (OUTF32) ((float*)C)[cb + idx] = v;
        else        ((u16*)C)[cb + idx] = f2b(v);
      }
    }
  }
}

// ---------------------------------------------------------------------------
// GroupNorm, f32 input [n][c][p] -> bf16 out TRANSPOSED to [n][p][c].
// One block per (n, g); 16 channels x 1024 pixels per group.
// ---------------------------------------------------------------------------
__global__ __launch_bounds__(256)
void groupnorm_f32(const float* __restrict__ x, const float* __restrict__ gamma,
                   const float* __restrict__ beta, u16* __restrict__ out)
{
  const int C = 512, HW = 1024;
  const int n = blockIdx.x >> 5, g = blockIdx.x & 31;
  const float* xg = x + ((long)n * C + g * 16) * HW;
  const int t = threadIdx.x;
  float s = 0.f, ss = 0.f;
  for (int ch = t; ch < 4096; ch += 256) {            // 4096 float4 chunks
    float4 u = *(const float4*)(xg + ch * 4);
    s += u.x + u.y + u.z + u.w;
    ss += u.x * u.x + u.y * u.y + u.z * u.z + u.w * u.w;
  }
#pragma unroll
  for (int off = 32; off > 0; off >>= 1) { s += __shfl_xor(s, off); ss += __shfl_xor(ss, off); }
  __shared__ float rs[4], rss[4];
  if ((t & 63) == 0) { rs[t >> 6] = s; rss[t >> 6] = ss; }
  __syncthreads();
  s  = rs[0] + rs[1] + rs[2] + rs[3];
  ss = rss[0] + rss[1] + rss[2] + rss[3];
  const float mu = s * (1.f / 16384.f);
  const float var = ss * (1.f / 16384.f) - mu * mu;
  const float rstd = rsqrtf(var + 1e-6f);
  float gm[16], bt[16];
#pragma unroll
  for (int i = 0; i < 16; ++i) {
    float ga = gamma[g * 16 + i];
    gm[i] = ga * rstd;
    bt[i] = beta[g * 16 + i] - mu * ga * rstd;
  }
  for (int p = t; p < 1024; p += 256) {
    alignas(16) u16 vals[16];
#pragma unroll
    for (int i = 0; i < 16; ++i)
      vals[i] = f2b(xg[(long)i * HW + p] * gm[i] + bt[i]);
    u16* dst = out + ((long)n * HW + p) * C + g * 16;
    *(uint4*)dst       = *(const uint4*)&vals[0];
    *(uint4*)(dst + 8) = *(const uint4*)&vals[8];
  }
}

// Same, bf16 input [n][c][p] -> bf16 out [n][p][c].
__global__ __launch_bounds__(256)
void groupnorm_bf16(const u16* __restrict__ x, const float* __restrict__ gamma,
                    const float* __restrict__ beta, u16* __restrict__ out)
{
  const int C = 512, HW = 1024;
  const int n = blockIdx.x >> 5, g = blockIdx.x & 31;
  const u16* xg = x + ((long)n * C + g * 16) * HW;
  const int t = threadIdx.x;
  float s = 0.f, ss = 0.f;
  for (int ch = t; ch < 2048; ch += 256) {            // 2048 chunks of 8 bf16
    uint4 u = *(const uint4*)(xg + ch * 8);
    uint32_t w[4] = {u.x, u.y, u.z, u.w};
#pragma unroll
    for (int k = 0; k < 4; ++k) {
      float f0 = __uint_as_float(w[k] << 16);
      float f1 = __uint_as_float(w[k] & 0xffff0000u);
      s += f0 + f1; ss += f0 * f0 + f1 * f1;
    }
  }
#pragma unroll
  for (int off = 32; off > 0; off >>= 1) { s += __shfl_xor(s, off); ss += __shfl_xor(ss, off); }
  __shared__ float rs[4], rss[4];
  if ((t & 63) == 0) { rs[t >> 6] = s; rss[t >> 6] = ss; }
  __syncthreads();
  s  = rs[0] + rs[1] + rs[2] + rs[3];
  ss = rss[0] + rss[1] + rss[2] + rss[3];
  const float mu = s * (1.f / 16384.f);
  const float var = ss * (1.f / 16384.f) - mu * mu;
  const float rstd = rsqrtf(var + 1e-6f);
  float gm[16], bt[16];
#pragma unroll
  for (int i = 0; i < 16; ++i) {
    float ga = gamma[g * 16 + i];
    gm[i] = ga * rstd;
    bt[i] = beta[g * 16 + i] - mu * ga * rstd;
  }
  for (int p = t; p < 1024; p += 256) {
    alignas(16) u16 vals[16];
#pragma unroll
    for (int i = 0; i < 16; ++i)
      vals[i] = f2b(b2f(xg[(long)i * HW + p]) * gm[i] + bt[i]);
    u16* dst = out + ((long)n * HW + p) * C + g * 16;
    *(uint4*)dst       = *(const uint4*)&vals[0];
    *(uint4*)(dst + 8) = *(const uint4*)&vals[8];
  }
}

// ---------------------------------------------------------------------------
// In-place softmax over rows of 1024 bf16. One block per row.
// ---------------------------------------------------------------------------
__global__ __launch_bounds__(256)
void softmax1024(u16* __restrict__ data)
{
  u16* row = data + (long)blockIdx.x * 1024;
  const int t = threadIdx.x;
  uint2 u = *(const uint2*)(row + t * 4);
  float v[4];
  v[0] = __uint_as_float(u.x << 16); v[1] = __uint_as_float(u.x & 0xffff0000u);
  v[2] = __uint_as_float(u.y << 16); v[3] = __uint_as_float(u.y & 0xffff0000u);
  float mx = fmaxf(fmaxf(v[0], v[1]), fmaxf(v[2], v[3]));
#pragma unroll
  for (int off = 32; off > 0; off >>= 1) mx = fmaxf(mx, __shfl_xor(mx, off));
  __shared__ float red[8];
  if ((t & 63) == 0) red[t >> 6] = mx;
  __syncthreads();
  mx = fmaxf(fmaxf(red[0], red[1]), fmaxf(red[2], red[3]));
  float e[4]; float s = 0.f;
#pragma unroll
  for (int k = 0; k < 4; ++k) { e[k] = __expf(v[k] - mx); s += e[k]; }
#pragma unroll
  for (int off = 32; off > 0; off >>= 1) s += __shfl_xor(s, off);
  if ((t & 63) == 0) red[4 + (t >> 6)] = s;
  __syncthreads();
  s = red[4] + red[5] + red[6] + red[7];
  float inv = 1.f / s;
  uint2 o;
  o.x = (uint32_t)f2b(e[0] * inv) | ((uint32_t)f2b(e[1] * inv) << 16);
  o.y = (uint32_t)f2b(e[2] * inv) | ((uint32_t)f2b(e[3] * inv) << 16);
  *(uint2*)(row + t * 4) = o;
}

// ---------------------------------------------------------------------------
// Temporal attention: per pixel (b,p), 5x5 attention over frames.
// q5,k5,v5: [20][512][1024] bf16 (c-major, n=b*5+f). htp out: [20][1024][512].
// Block: 16 pixels x 16 channel-groups (32 ch each). 256 blocks.
// ---------------------------------------------------------------------------
__global__ __launch_bounds__(256)
void temporal_attn(const u16* __restrict__ q5, const u16* __restrict__ k5,
                   const u16* __restrict__ v5, u16* __restrict__ htp)
{
  const int C = 512, HW = 1024;
  const int t = threadIdx.x;
  const int px = t & 15, cl = t >> 4;
  const int pxg = blockIdx.x * 16 + px;
  const int b = pxg >> 10, p = pxg & 1023;
  const long base = (long)b * 5 * C * HW + p;
  float sc[25];
#pragma unroll
  for (int i = 0; i < 25; ++i) sc[i] = 0.f;
  const int c0 = cl * 32;
  for (int c = c0; c < c0 + 32; ++c) {
    float qv[5], kv[5];
#pragma unroll
    for (int f = 0; f < 5; ++f) {
      long off = base + ((long)f * C + c) * HW;
      qv[f] = b2f(q5[off]);
      kv[f] = b2f(k5[off]);
    }
#pragma unroll
    for (int i = 0; i < 5; ++i)
#pragma unroll
      for (int j = 0; j < 5; ++j) sc[i * 5 + j] += qv[i] * kv[j];
  }
  __shared__ float sred[16][16][26];
#pragma unroll
  for (int i = 0; i < 25; ++i) sred[cl][px][i] = sc[i];
  __syncthreads();
  __shared__ float att_s[16][26];
  const float scale = 0.04419417382415922f;  // 512^-0.5
  for (int idx = cl; idx < 25; idx += 16) {
    float a = 0.f;
#pragma unroll
    for (int c = 0; c < 16; ++c) a += sred[c][px][idx];
    att_s[px][idx] = a * scale;
  }
  __syncthreads();
  if (t < 16) {
#pragma unroll
    for (int i = 0; i < 5; ++i) {
      float m = att_s[t][i * 5];
      for (int j = 1; j < 5; ++j) m = fmaxf(m, att_s[t][i * 5 + j]);
      float e[5], ssum = 0.f;
      for (int j = 0; j < 5; ++j) { e[j] = __expf(att_s[t][i * 5 + j] - m); ssum += e[j]; }
      float inv = 1.f / ssum;
      for (int j = 0; j < 5; ++j) att_s[t][i * 5 + j] = e[j] * inv;
    }
  }
  __syncthreads();
  float att[25];
#pragma unroll
  for (int i = 0; i < 25; ++i) att[i] = att_s[px][i];
  for (int cc0 = c0; cc0 < c0 + 32; cc0 += 8) {
    alignas(16) u16 ob[5][8];
#pragma unroll
    for (int cc = 0; cc < 8; ++cc) {
      float vv[5];
#pragma unroll
      for (int s = 0; s < 5; ++s) vv[s] = b2f(v5[base + ((long)s * C + cc0 + cc) * HW]);
#pragma unroll
      for (int i = 0; i < 5; ++i) {
        float o = 0.f;
#pragma unroll
        for (int s = 0; s < 5; ++s) o += att[i * 5 + s] * vv[s];
        ob[i][cc] = f2b(o);
      }
    }
#pragma unroll
    for (int i = 0; i < 5; ++i)
      *(uint4*)(htp + ((long)(b * 5 + i) * HW + p) * C + cc0) = *(const uint4*)ob[i];
  }
}

// ---------------------------------------------------------------------------
extern "C" void kernel_launch(void* const* d_in, const int* in_sizes, int n_in,
                              void* d_out, int out_size, void* d_ws, size_t ws_size,
                              hipStream_t stream)
{
  const float* x   = (const float*)d_in[0];
  const float* wq  = (const float*)d_in[1];
  const float* bq  = (const float*)d_in[2];
  const float* wk  = (const float*)d_in[3];
  const float* bk  = (const float*)d_in[4];
  const float* wv  = (const float*)d_in[5];
  const float* bv  = (const float*)d_in[6];
  const float* wo  = (const float*)d_in[7];
  const float* bo  = (const float*)d_in[8];
  const float* wqt = (const float*)d_in[9];
  const float* bqt = (const float*)d_in[10];
  const float* wkt = (const float*)d_in[11];
  const float* bkt = (const float*)d_in[12];
  const float* wvt = (const float*)d_in[13];
  const float* bvt = (const float*)d_in[14];
  const float* wot = (const float*)d_in[15];
  const float* bot = (const float*)d_in[16];
  const float* gs  = (const float*)d_in[17];
  const float* bs  = (const float*)d_in[18];
  const float* gt  = (const float*)d_in[19];
  const float* btt = (const float*)d_in[20];

  // bf16 slots: 3 in ws (W0..W2) + weights region; 2 carved from d_out (D0,D1).
  const long U = 20l * 1024 * 512;          // 10,485,760 elements per slot
  u16* W0 = (u16*)d_ws;
  u16* W1 = W0 + U;
  u16* W2 = W0 + 2 * U;
  u16* Wt = W0 + 3 * U;                     // 8 x 262144 bf16 weights (4 MB)
  u16* D0 = (u16*)d_out;                    // d_out = 41,943,040 B = 2 slots
  u16* D1 = D0 + U;
  u16* wq_b  = Wt;
  u16* wk_b  = Wt + 1 * 262144;
  u16* wv_b  = Wt + 2 * 262144;
  u16* wo_b  = Wt + 3 * 262144;
  u16* wqt_b = Wt + 4 * 262144;
  u16* wkt_b = Wt + 5 * 262144;
  u16* wvt_b = Wt + 6 * 262144;
  u16* wot_b = Wt + 7 * 262144;

  const long S  = 524288;                   // 1024*512 per-batch stride
  const long S2 = 1048576;                  // 1024*1024 per-batch stride
  const long HB = 10 * S;                   // half-batch offset (activations)
  const float scale = 0.04419417382415922f; // 512^-0.5
  dim3 blk(256);

  convert_w8<<<1024, blk, 0, stream>>>(wq, wk, wv, wo, wqt, wkt, wvt, wot, Wt);

  // hn = GroupNorm_s(x) -> W0 [n][p][c]
  groupnorm_f32<<<640, blk, 0, stream>>>(x, gs, bs, W0);
  // q,k: M=p(1024), N=o(512): A=hn, Bt=W -> [p][c]
  gemm_bt<0, 2, 0><<<dim3(4, 8, 20), blk, 0, stream>>>(W0, S, wq_b, 0, W1, S, bq, nullptr, 0, 512, 512, 1.f);
  gemm_bt<0, 2, 0><<<dim3(4, 8, 20), blk, 0, stream>>>(W0, S, wk_b, 0, W2, S, bk, nullptr, 0, 512, 512, 1.f);
  // v: M=o(512), N=p(1024): A=W, Bt=hn -> [c][p] into D0 (d_out scratch)
  gemm_bt<0, 1, 0><<<dim3(8, 4, 20), blk, 0, stream>>>(wv_b, 0, W0, S, D0, S, bv, nullptr, 0, 1024, 512, 1.f);
  // scores = scale * q.k^T, batch-halved: bz 0..9 -> W0 (hn dead), 10..19 -> D1
  gemm_bt<0, 0, 0><<<dim3(8, 8, 10), blk, 0, stream>>>(W1, S, W2, S, W0, S2, nullptr, nullptr, 0, 1024, 512, scale);
  gemm_bt<0, 0, 0><<<dim3(8, 8, 10), blk, 0, stream>>>(W1 + HB, S, W2 + HB, S, D1, S2, nullptr, nullptr, 0, 1024, 512, scale);
  softmax1024<<<10240, blk, 0, stream>>>(W0);
  softmax1024<<<10240, blk, 0, stream>>>(D1);
  // hsp^T = att . v^T: M=pq(1024), N=c(512), K=pk(1024) -> W1 [p][c] (q dead)
  gemm_bt<0, 0, 0><<<dim3(4, 8, 10), blk, 0, stream>>>(W0, S2, D0, S, W1, S, nullptr, nullptr, 0, 512, 1024, 1.f);
  gemm_bt<0, 0, 0><<<dim3(4, 8, 10), blk, 0, stream>>>(D1, S2, D0 + HB, S, W1 + HB, S, nullptr, nullptr, 0, 512, 1024, 1.f);
  // spatio = x + wo.hsp + bo -> W2 [c][p] bf16 (k dead)
  gemm_bt<0, 1, 1><<<dim3(8, 4, 20), blk, 0, stream>>>(wo_b, 0, W1, S, W2, S, bo, x, S, 1024, 512, 1.f);
  // hn_t = GroupNorm_t(spatio) -> W0 [n][p][c] (scores half1 dead)
  groupnorm_bf16<<<640, blk, 0, stream>>>(W2, gt, btt, W0);
  // q5 -> D0 (v dead), k5 -> D1 (scores half2 dead), v5 -> W1 (hsp dead); [c][p]
  gemm_bt<0, 1, 0><<<dim3(8, 4, 20), blk, 0, stream>>>(wqt_b, 0, W0, S, D0, S, bqt, nullptr, 0, 1024, 512, 1.f);
  gemm_bt<0, 1, 0><<<dim3(8, 4, 20), blk, 0, stream>>>(wkt_b, 0, W0, S, D1, S, bkt, nullptr, 0, 1024, 512, 1.f);
  gemm_bt<0, 1, 0><<<dim3(8, 4, 20), blk, 0, stream>>>(wvt_b, 0, W0, S, W1, S, bvt, nullptr, 0, 1024, 512, 1.f);
  // per-pixel 5x5 temporal attention -> W2 htp [p][c] (spatio dead)
  temporal_attn<<<256, blk, 0, stream>>>(D0, D1, W1, W2);
  // out = x + wot.htp + bot -> d_out f32 (overwrites D0/D1; q5,k5 dead)
  gemm_bt<1, 1, 1><<<dim3(8, 4, 20), blk, 0, stream>>>(wot_b, 0, W2, S, (float*)d_out, S, bot, x, S, 1024, 512, 1.f);
}

// Round 4
// 525.787 us; speedup vs baseline: 1.1231x; 1.1231x over previous
//
#include <hip/hip_runtime.h>
#include <hip/hip_bf16.h>
#include <stdint.h>

typedef unsigned short u16;
typedef __attribute__((ext_vector_type(8))) short bf16x8;
typedef __attribute__((ext_vector_type(4))) float f32x4;

#define DI __device__ __forceinline__

DI float b2f(u16 u) { return __uint_as_float(((uint32_t)u) << 16); }
DI u16 f2b(float f) {
  uint32_t u = __float_as_uint(f);
  u += 0x7fff + ((u >> 16) & 1);   // RNE
  return (u16)(u >> 16);
}

DI void gld_lds16(const u16* g, u16* l) {
  __builtin_amdgcn_global_load_lds((const __attribute__((address_space(1))) void*)g,
                                   (__attribute__((address_space(3))) void*)l,
                                   16, 0, 0);
}

// ---------------------------------------------------------------------------
// Convert 8 weight matrices (512x512 f32) to bf16, concatenated at dst.
// ---------------------------------------------------------------------------
__global__ __launch_bounds__(256)
void convert_w8(const float* __restrict__ w0, const float* __restrict__ w1,
                const float* __restrict__ w2, const float* __restrict__ w3,
                const float* __restrict__ w4, const float* __restrict__ w5,
                const float* __restrict__ w6, const float* __restrict__ w7,
                u16* __restrict__ dst)
{
  const float* srcs[8] = {w0, w1, w2, w3, w4, w5, w6, w7};
  const int mat = blockIdx.x >> 7;                 // 128 blocks per matrix
  const int i = (((blockIdx.x & 127) << 8) + threadIdx.x) * 8;
  const float* s = srcs[mat];
  float4 a = *(const float4*)(s + i);
  float4 b = *(const float4*)(s + i + 4);
  alignas(16) u16 v[8] = {f2b(a.x), f2b(a.y), f2b(a.z), f2b(a.w),
                          f2b(b.x), f2b(b.y), f2b(b.z), f2b(b.w)};
  *(uint4*)(dst + (long)mat * 262144 + i) = *(const uint4*)v;
}

// ---------------------------------------------------------------------------
// Batched GEMM: out[m][n] = alpha * sum_k A[m][k]*Bt[n][k]  (+bias, +resid)
// A,Bt bf16; bias/resid f32; out bf16 or f32 (OUTF32).
// BM=BN=128, BK=32, 256 threads (4 waves as 2x2 of 64x64), 16x16x32 bf16 MFMA.
// m97 recipe: global_load_lds width=16 async staging (wave-uniform LDS base,
// lane x 16B scatter -> contiguous row-major [128][32] tile).
// BIASMODE: 0 none, 1 bias[row], 2 bias[col].
// ---------------------------------------------------------------------------
template<int OUTF32, int BIASMODE, int RESID>
__global__ __launch_bounds__(256)
void gemm_bt(const u16* __restrict__ A, long sA,
             const u16* __restrict__ B, long sB,
             void* __restrict__ C, long sC,
             const float* __restrict__ bias,
             const float* __restrict__ resid, long sR,
             int N, int K, float alpha)
{
  __shared__ u16 lA[128 * 32];
  __shared__ u16 lB[128 * 32];
  const int t = threadIdx.x;
  const int lane = t & 63;
  const int m0 = blockIdx.y * 128, n0 = blockIdx.x * 128;
  const long bz = blockIdx.z;
  const u16* Ab = A + bz * sA;
  const u16* Bb = B + bz * sB;

  const int row = t >> 2;          // 0..63 (wave covers 16 rows x 4 k-chunks)
  const int kc  = (t & 3) * 8;     // k-element offset of this thread's 16B chunk
  const int wid = t >> 6;
  u16* lAw = lA + wid * 512;       // wave-uniform LDS base; HW adds lane*16B
  u16* lBw = lB + wid * 512;

  f32x4 acc[4][4];
#pragma unroll
  for (int i = 0; i < 4; ++i)
#pragma unroll
    for (int j = 0; j < 4; ++j) acc[i][j] = (f32x4){0.f, 0.f, 0.f, 0.f};

  const int ml = lane & 15, qd = lane >> 4;
  const int wm = (wid >> 1) * 64, wn = (wid & 1) * 64;

  for (int k0 = 0; k0 < K; k0 += 32) {
    gld_lds16(Ab + (long)(m0 + row) * K + (k0 + kc), lAw);
    gld_lds16(Ab + (long)(m0 + 64 + row) * K + (k0 + kc), lAw + 2048);
    gld_lds16(Bb + (long)(n0 + row) * K + (k0 + kc), lBw);
    gld_lds16(Bb + (long)(n0 + 64 + row) * K + (k0 + kc), lBw + 2048);
    __syncthreads();
    bf16x8 af[4], bfr[4];
#pragma unroll
    for (int i = 0; i < 4; ++i)
      af[i] = *(const bf16x8*)&lA[(wm + i * 16 + ml) * 32 + qd * 8];
#pragma unroll
    for (int j = 0; j < 4; ++j)
      bfr[j] = *(const bf16x8*)&lB[(wn + j * 16 + ml) * 32 + qd * 8];
#pragma unroll
    for (int i = 0; i < 4; ++i)
#pragma unroll
      for (int j = 0; j < 4; ++j)
        acc[i][j] = __builtin_amdgcn_mfma_f32_16x16x32_bf16(af[i], bfr[j], acc[i][j], 0, 0, 0);
    __syncthreads();
  }

  const long cb = bz * sC;
#pragma unroll
  for (int i = 0; i < 4; ++i) {
#pragma unroll
    for (int j = 0; j < 4; ++j) {
#pragma unroll
      for (int r = 0; r < 4; ++r) {
        int rr = m0 + wm + i * 16 + qd * 4 + r;   // C/D row = quad*4+reg (m89)
        int cc = n0 + wn + j * 16 + ml;           // C/D col = lane&15
        float v = acc[i][j][r] * alpha;
        if (BIASMODE == 1) v += bias[rr];
        if (BIASMODE == 2) v += bias[cc];
        long idx = (long)rr * N + cc;
        if (RESID) v += resid[bz * sR + idx];
        if (OUTF32) ((float*)C)[cb + idx] = v;
        else        ((u16*)C)[cb + idx] = f2b(v);
      }
    }
  }
}

// ---------------------------------------------------------------------------
// GroupNorm, f32 input [n][c][p] -> bf16 out TRANSPOSED to [n][p][c].
// ---------------------------------------------------------------------------
__global__ __launch_bounds__(256)
void groupnorm_f32(const float* __restrict__ x, const float* __restrict__ gamma,
                   const float* __restrict__ beta, u16* __restrict__ out)
{
  const int C = 512, HW = 1024;
  const int n = blockIdx.x >> 5, g = blockIdx.x & 31;
  const float* xg = x + ((long)n * C + g * 16) * HW;
  const int t = threadIdx.x;
  float s = 0.f, ss = 0.f;
  for (int ch = t; ch < 4096; ch += 256) {
    float4 u = *(const float4*)(xg + ch * 4);
    s += u.x + u.y + u.z + u.w;
    ss += u.x * u.x + u.y * u.y + u.z * u.z + u.w * u.w;
  }
#pragma unroll
  for (int off = 32; off > 0; off >>= 1) { s += __shfl_xor(s, off); ss += __shfl_xor(ss, off); }
  __shared__ float rs[4], rss[4];
  if ((t & 63) == 0) { rs[t >> 6] = s; rss[t >> 6] = ss; }
  __syncthreads();
  s  = rs[0] + rs[1] + rs[2] + rs[3];
  ss = rss[0] + rss[1] + rss[2] + rss[3];
  const float mu = s * (1.f / 16384.f);
  const float var = ss * (1.f / 16384.f) - mu * mu;
  const float rstd = rsqrtf(var + 1e-6f);
  float gm[16], bt[16];
#pragma unroll
  for (int i = 0; i < 16; ++i) {
    float ga = gamma[g * 16 + i];
    gm[i] = ga * rstd;
    bt[i] = beta[g * 16 + i] - mu * ga * rstd;
  }
  for (int p = t; p < 1024; p += 256) {
    alignas(16) u16 vals[16];
#pragma unroll
    for (int i = 0; i < 16; ++i)
      vals[i] = f2b(xg[(long)i * HW + p] * gm[i] + bt[i]);
    u16* dst = out + ((long)n * HW + p) * C + g * 16;
    *(uint4*)dst       = *(const uint4*)&vals[0];
    *(uint4*)(dst + 8) = *(const uint4*)&vals[8];
  }
}

// Same, bf16 input [n][c][p] -> bf16 out [n][p][c].
__global__ __launch_bounds__(256)
void groupnorm_bf16(const u16* __restrict__ x, const float* __restrict__ gamma,
                    const float* __restrict__ beta, u16* __restrict__ out)
{
  const int C = 512, HW = 1024;
  const int n = blockIdx.x >> 5, g = blockIdx.x & 31;
  const u16* xg = x + ((long)n * C + g * 16) * HW;
  const int t = threadIdx.x;
  float s = 0.f, ss = 0.f;
  for (int ch = t; ch < 2048; ch += 256) {
    uint4 u = *(const uint4*)(xg + ch * 8);
    uint32_t w[4] = {u.x, u.y, u.z, u.w};
#pragma unroll
    for (int k = 0; k < 4; ++k) {
      float f0 = __uint_as_float(w[k] << 16);
      float f1 = __uint_as_float(w[k] & 0xffff0000u);
      s += f0 + f1; ss += f0 * f0 + f1 * f1;
    }
  }
#pragma unroll
  for (int off = 32; off > 0; off >>= 1) { s += __shfl_xor(s, off); ss += __shfl_xor(ss, off); }
  __shared__ float rs[4], rss[4];
  if ((t & 63) == 0) { rs[t >> 6] = s; rss[t >> 6] = ss; }
  __syncthreads();
  s  = rs[0] + rs[1] + rs[2] + rs[3];
  ss = rss[0] + rss[1] + rss[2] + rss[3];
  const float mu = s * (1.f / 16384.f);
  const float var = ss * (1.f / 16384.f) - mu * mu;
  const float rstd = rsqrtf(var + 1e-6f);
  float gm[16], bt[16];
#pragma unroll
  for (int i = 0; i < 16; ++i) {
    float ga = gamma[g * 16 + i];
    gm[i] = ga * rstd;
    bt[i] = beta[g * 16 + i] - mu * ga * rstd;
  }
  for (int p = t; p < 1024; p += 256) {
    alignas(16) u16 vals[16];
#pragma unroll
    for (int i = 0; i < 16; ++i)
      vals[i] = f2b(b2f(xg[(long)i * HW + p]) * gm[i] + bt[i]);
    u16* dst = out + ((long)n * HW + p) * C + g * 16;
    *(uint4*)dst       = *(const uint4*)&vals[0];
    *(uint4*)(dst + 8) = *(const uint4*)&vals[8];
  }
}

// ---------------------------------------------------------------------------
// In-place softmax over rows of 1024 bf16. One block per row.
// ---------------------------------------------------------------------------
__global__ __launch_bounds__(256)
void softmax1024(u16* __restrict__ data)
{
  u16* row = data + (long)blockIdx.x * 1024;
  const int t = threadIdx.x;
  uint2 u = *(const uint2*)(row + t * 4);
  float v[4];
  v[0] = __uint_as_float(u.x << 16); v[1] = __uint_as_float(u.x & 0xffff0000u);
  v[2] = __uint_as_float(u.y << 16); v[3] = __uint_as_float(u.y & 0xffff0000u);
  float mx = fmaxf(fmaxf(v[0], v[1]), fmaxf(v[2], v[3]));
#pragma unroll
  for (int off = 32; off > 0; off >>= 1) mx = fmaxf(mx, __shfl_xor(mx, off));
  __shared__ float red[8];
  if ((t & 63) == 0) red[t >> 6] = mx;
  __syncthreads();
  mx = fmaxf(fmaxf(red[0], red[1]), fmaxf(red[2], red[3]));
  float e[4]; float s = 0.f;
#pragma unroll
  for (int k = 0; k < 4; ++k) { e[k] = __expf(v[k] - mx); s += e[k]; }
#pragma unroll
  for (int off = 32; off > 0; off >>= 1) s += __shfl_xor(s, off);
  if ((t & 63) == 0) red[4 + (t >> 6)] = s;
  __syncthreads();
  s = red[4] + red[5] + red[6] + red[7];
  float inv = 1.f / s;
  uint2 o;
  o.x = (uint32_t)f2b(e[0] * inv) | ((uint32_t)f2b(e[1] * inv) << 16);
  o.y = (uint32_t)f2b(e[2] * inv) | ((uint32_t)f2b(e[3] * inv) << 16);
  *(uint2*)(row + t * 4) = o;
}

// ---------------------------------------------------------------------------
// Temporal attention v2: one WAVE per pixel (b,p); q5,k5,v5,htp all [20][1024][512]
// ([p][c], p-major). Lane l owns channels 8l..8l+7: bf16x8 loads (16B/lane,
// coalesced, no LDS). 25 scores butterfly-reduced via __shfl_xor; softmax
// replicated per-lane; PV in registers; 16B/lane stores.
// Grid: 1024 blocks x 256 (4 waves = 4 pixels per block).
// ---------------------------------------------------------------------------
__global__ __launch_bounds__(256)
void temporal_attn(const u16* __restrict__ q5, const u16* __restrict__ k5,
                   const u16* __restrict__ v5, u16* __restrict__ htp)
{
  const int C = 512, HW = 1024;
  const int t = threadIdx.x;
  const int wv = t >> 6, lane = t & 63;
  const int pix = blockIdx.x * 4 + wv;      // 0..4095 = (b, p)
  const int b = pix >> 10, p = pix & 1023;
  const long fs = (long)HW * C;             // frame stride
  const long rowbase = ((long)b * 5 * HW + p) * C + lane * 8;

  float qf[5][8], kf[5][8];
#pragma unroll
  for (int f = 0; f < 5; ++f) {
    bf16x8 qv = *(const bf16x8*)(q5 + rowbase + f * fs);
    bf16x8 kv = *(const bf16x8*)(k5 + rowbase + f * fs);
#pragma unroll
    for (int u = 0; u < 8; ++u) { qf[f][u] = b2f((u16)qv[u]); kf[f][u] = b2f((u16)kv[u]); }
  }
  float sc[25];
#pragma unroll
  for (int i = 0; i < 5; ++i)
#pragma unroll
    for (int j = 0; j < 5; ++j) {
      float a = 0.f;
#pragma unroll
      for (int u = 0; u < 8; ++u) a += qf[i][u] * kf[j][u];
      sc[i * 5 + j] = a;
    }
#pragma unroll
  for (int m = 1; m < 64; m <<= 1)
#pragma unroll
    for (int s = 0; s < 25; ++s) sc[s] += __shfl_xor(sc[s], m);

  const float scale = 0.04419417382415922f;  // 512^-0.5
  float att[5][5];
#pragma unroll
  for (int i = 0; i < 5; ++i) {
    float m = sc[i * 5];
#pragma unroll
    for (int j = 1; j < 5; ++j) m = fmaxf(m, sc[i * 5 + j]);
    float ssum = 0.f;
#pragma unroll
    for (int j = 0; j < 5; ++j) { att[i][j] = __expf((sc[i * 5 + j] - m) * scale); ssum += att[i][j]; }
    float inv = 1.f / ssum;
#pragma unroll
    for (int j = 0; j < 5; ++j) att[i][j] *= inv;
  }

  float of[5][8];
#pragma unroll
  for (int i = 0; i < 5; ++i)
#pragma unroll
    for (int u = 0; u < 8; ++u) of[i][u] = 0.f;
#pragma unroll
  for (int s = 0; s < 5; ++s) {
    bf16x8 vv = *(const bf16x8*)(v5 + rowbase + s * fs);
#pragma unroll
    for (int u = 0; u < 8; ++u) {
      float vf = b2f((u16)vv[u]);
#pragma unroll
      for (int i = 0; i < 5; ++i) of[i][u] += att[i][s] * vf;
    }
  }
#pragma unroll
  for (int i = 0; i < 5; ++i) {
    alignas(16) u16 ob[8];
#pragma unroll
    for (int u = 0; u < 8; ++u) ob[u] = f2b(of[i][u]);
    *(uint4*)(htp + rowbase + i * fs) = *(const uint4*)ob;
  }
}

// ---------------------------------------------------------------------------
extern "C" void kernel_launch(void* const* d_in, const int* in_sizes, int n_in,
                              void* d_out, int out_size, void* d_ws, size_t ws_size,
                              hipStream_t stream)
{
  const float* x   = (const float*)d_in[0];
  const float* wq  = (const float*)d_in[1];
  const float* bq  = (const float*)d_in[2];
  const float* wk  = (const float*)d_in[3];
  const float* bk  = (const float*)d_in[4];
  const float* wv  = (const float*)d_in[5];
  const float* bv  = (const float*)d_in[6];
  const float* wo  = (const float*)d_in[7];
  const float* bo  = (const float*)d_in[8];
  const float* wqt = (const float*)d_in[9];
  const float* bqt = (const float*)d_in[10];
  const float* wkt = (const float*)d_in[11];
  const float* bkt = (const float*)d_in[12];
  const float* wvt = (const float*)d_in[13];
  const float* bvt = (const float*)d_in[14];
  const float* wot = (const float*)d_in[15];
  const float* bot = (const float*)d_in[16];
  const float* gs  = (const float*)d_in[17];
  const float* bs  = (const float*)d_in[18];
  const float* gt  = (const float*)d_in[19];
  const float* btt = (const float*)d_in[20];

  // bf16 slots: 3 in ws (W0..W2) + weights region; 2 carved from d_out (D0,D1).
  const long U = 20l * 1024 * 512;          // elements per slot (20 MB)
  u16* W0 = (u16*)d_ws;
  u16* W1 = W0 + U;
  u16* W2 = W0 + 2 * U;
  u16* Wt = W0 + 3 * U;                     // 8 x 262144 bf16 weights (4 MB)
  u16* D0 = (u16*)d_out;                    // d_out = 41,943,040 B = 2 slots
  u16* D1 = D0 + U;
  u16* wq_b  = Wt;
  u16* wk_b  = Wt + 1 * 262144;
  u16* wv_b  = Wt + 2 * 262144;
  u16* wo_b  = Wt + 3 * 262144;
  u16* wqt_b = Wt + 4 * 262144;
  u16* wkt_b = Wt + 5 * 262144;
  u16* wvt_b = Wt + 6 * 262144;
  u16* wot_b = Wt + 7 * 262144;

  const long S  = 524288;                   // 1024*512 per-batch stride
  const long S2 = 1048576;                  // 1024*1024 per-batch stride
  const long HB = 10 * S;                   // half-batch offset (activations)
  const float scale = 0.04419417382415922f; // 512^-0.5
  dim3 blk(256);

  convert_w8<<<1024, blk, 0, stream>>>(wq, wk, wv, wo, wqt, wkt, wvt, wot, Wt);

  // hn = GroupNorm_s(x) -> W0 [n][p][c]
  groupnorm_f32<<<640, blk, 0, stream>>>(x, gs, bs, W0);
  // q,k: M=p(1024), N=o(512): A=hn, Bt=W -> [p][c]
  gemm_bt<0, 2, 0><<<dim3(4, 8, 20), blk, 0, stream>>>(W0, S, wq_b, 0, W1, S, bq, nullptr, 0, 512, 512, 1.f);
  gemm_bt<0, 2, 0><<<dim3(4, 8, 20), blk, 0, stream>>>(W0, S, wk_b, 0, W2, S, bk, nullptr, 0, 512, 512, 1.f);
  // v: M=o(512), N=p(1024): A=W, Bt=hn -> [c][p] into D0 (d_out scratch)
  gemm_bt<0, 1, 0><<<dim3(8, 4, 20), blk, 0, stream>>>(wv_b, 0, W0, S, D0, S, bv, nullptr, 0, 1024, 512, 1.f);
  // scores = scale * q.k^T, batch-halved: bz 0..9 -> W0 (hn dead), 10..19 -> D1
  gemm_bt<0, 0, 0><<<dim3(8, 8, 10), blk, 0, stream>>>(W1, S, W2, S, W0, S2, nullptr, nullptr, 0, 1024, 512, scale);
  gemm_bt<0, 0, 0><<<dim3(8, 8, 10), blk, 0, stream>>>(W1 + HB, S, W2 + HB, S, D1, S2, nullptr, nullptr, 0, 1024, 512, scale);
  softmax1024<<<10240, blk, 0, stream>>>(W0);
  softmax1024<<<10240, blk, 0, stream>>>(D1);
  // hsp^T = att . v^T: M=pq(1024), N=c(512), K=pk(1024) -> W1 [p][c] (q dead)
  gemm_bt<0, 0, 0><<<dim3(4, 8, 10), blk, 0, stream>>>(W0, S2, D0, S, W1, S, nullptr, nullptr, 0, 512, 1024, 1.f);
  gemm_bt<0, 0, 0><<<dim3(4, 8, 10), blk, 0, stream>>>(D1, S2, D0 + HB, S, W1 + HB, S, nullptr, nullptr, 0, 512, 1024, 1.f);
  // spatio = x + wo.hsp + bo -> W2 [c][p] bf16 (k dead)
  gemm_bt<0, 1, 1><<<dim3(8, 4, 20), blk, 0, stream>>>(wo_b, 0, W1, S, W2, S, bo, x, S, 1024, 512, 1.f);
  // hn_t = GroupNorm_t(spatio) -> W0 [n][p][c] (scores half1 dead)
  groupnorm_bf16<<<640, blk, 0, stream>>>(W2, gt, btt, W0);
  // q5 -> D0 (v dead), k5 -> D1 (scores half2 dead), v5 -> W1 (hsp dead);
  // all M=p -> [p][c] layout for the wave-per-pixel temporal kernel.
  gemm_bt<0, 2, 0><<<dim3(4, 8, 20), blk, 0, stream>>>(W0, S, wqt_b, 0, D0, S, bqt, nullptr, 0, 512, 512, 1.f);
  gemm_bt<0, 2, 0><<<dim3(4, 8, 20), blk, 0, stream>>>(W0, S, wkt_b, 0, D1, S, bkt, nullptr, 0, 512, 512, 1.f);
  gemm_bt<0, 2, 0><<<dim3(4, 8, 20), blk, 0, stream>>>(W0, S, wvt_b, 0, W1, S, bvt, nullptr, 0, 512, 512, 1.f);
  // per-pixel 5x5 temporal attention -> W2 htp [p][c] (spatio dead)
  temporal_attn<<<1024, blk, 0, stream>>>(D0, D1, W1, W2);
  // out = x + wot.htp + bot -> d_out f32 (overwrites D0/D1; q5,k5 dead)
  gemm_bt<1, 1, 1><<<dim3(8, 4, 20), blk, 0, stream>>>(wot_b, 0, W2, S, (float*)d_out, S, bot, x, S, 1024, 512, 1.f);
}

// Round 5
// 478.205 us; speedup vs baseline: 1.2349x; 1.0995x over previous
//
#include <hip/hip_runtime.h>
#include <hip/hip_bf16.h>
#include <stdint.h>

typedef unsigned short u16;
typedef __attribute__((ext_vector_type(8))) short bf16x8;
typedef __attribute__((ext_vector_type(4))) float f32x4;

#define DI __device__ __forceinline__

DI float b2f(u16 u) { return __uint_as_float(((uint32_t)u) << 16); }
DI u16 f2b(float f) {
  uint32_t u = __float_as_uint(f);
  u += 0x7fff + ((u >> 16) & 1);   // RNE
  return (u16)(u >> 16);
}

DI void gld_lds16(const u16* g, u16* l) {
  __builtin_amdgcn_global_load_lds((const __attribute__((address_space(1))) void*)g,
                                   (__attribute__((address_space(3))) void*)l,
                                   16, 0, 0);
}

// ---------------------------------------------------------------------------
// Convert 8 weight matrices (512x512 f32) to bf16, concatenated at dst.
// Order: wq wk wv wo | wqt wkt wvt wot  (adjacency enables N=1024/1536 fusion)
// ---------------------------------------------------------------------------
__global__ __launch_bounds__(256)
void convert_w8(const float* __restrict__ w0, const float* __restrict__ w1,
                const float* __restrict__ w2, const float* __restrict__ w3,
                const float* __restrict__ w4, const float* __restrict__ w5,
                const float* __restrict__ w6, const float* __restrict__ w7,
                u16* __restrict__ dst)
{
  const float* srcs[8] = {w0, w1, w2, w3, w4, w5, w6, w7};
  const int mat = blockIdx.x >> 7;                 // 128 blocks per matrix
  const int i = (((blockIdx.x & 127) << 8) + threadIdx.x) * 8;
  const float* s = srcs[mat];
  float4 a = *(const float4*)(s + i);
  float4 b = *(const float4*)(s + i + 4);
  alignas(16) u16 v[8] = {f2b(a.x), f2b(a.y), f2b(a.z), f2b(a.w),
                          f2b(b.x), f2b(b.y), f2b(b.z), f2b(b.w)};
  *(uint4*)(dst + (long)mat * 262144 + i) = *(const uint4*)v;
}

// Pack 8 bias vectors (512 f32 each) contiguously: bq bk bv bo bqt bkt bvt bot
__global__ __launch_bounds__(256)
void pack_biases(const float* __restrict__ b0, const float* __restrict__ b1,
                 const float* __restrict__ b2, const float* __restrict__ b3,
                 const float* __restrict__ b4, const float* __restrict__ b5,
                 const float* __restrict__ b6, const float* __restrict__ b7,
                 float* __restrict__ dst)
{
  const float* srcs[8] = {b0, b1, b2, b3, b4, b5, b6, b7};
  const int t = threadIdx.x;
  for (int a = 0; a < 8; ++a)
    for (int i = t; i < 512; i += 256) dst[a * 512 + i] = srcs[a][i];
}

// ---------------------------------------------------------------------------
// Batched GEMM: out[m][n] = alpha * sum_k A[m*lda+k]*Bt[n*ldb+k]  (+bias,+resid)
// A,Bt bf16; bias/resid f32; out bf16 or f32 (OUTF32). ldC = N.
// BM=BN=128, BK=32, 256 threads (4 waves as 2x2 of 64x64), 16x16x32 bf16 MFMA.
// m97 recipe: global_load_lds width=16 async staging.
// BIASMODE: 0 none, 1 bias[row], 2 bias[col].
// ---------------------------------------------------------------------------
template<int OUTF32, int BIASMODE, int RESID>
__global__ __launch_bounds__(256)
void gemm_bt(const u16* __restrict__ A, long sA, long lda,
             const u16* __restrict__ B, long sB, long ldb,
             void* __restrict__ C, long sC,
             const float* __restrict__ bias,
             const float* __restrict__ resid, long sR,
             int N, int K, float alpha)
{
  __shared__ u16 lA[128 * 32];
  __shared__ u16 lB[128 * 32];
  const int t = threadIdx.x;
  const int lane = t & 63;
  const int m0 = blockIdx.y * 128, n0 = blockIdx.x * 128;
  const long bz = blockIdx.z;
  const u16* Ab = A + bz * sA;
  const u16* Bb = B + bz * sB;

  const int row = t >> 2;          // 0..63
  const int kc  = (t & 3) * 8;     // k-element offset of this thread's 16B chunk
  const int wid = t >> 6;
  u16* lAw = lA + wid * 512;       // wave-uniform LDS base; HW adds lane*16B
  u16* lBw = lB + wid * 512;

  f32x4 acc[4][4];
#pragma unroll
  for (int i = 0; i < 4; ++i)
#pragma unroll
    for (int j = 0; j < 4; ++j) acc[i][j] = (f32x4){0.f, 0.f, 0.f, 0.f};

  const int ml = lane & 15, qd = lane >> 4;
  const int wm = (wid >> 1) * 64, wn = (wid & 1) * 64;

  for (int k0 = 0; k0 < K; k0 += 32) {
    gld_lds16(Ab + (long)(m0 + row) * lda + (k0 + kc), lAw);
    gld_lds16(Ab + (long)(m0 + 64 + row) * lda + (k0 + kc), lAw + 2048);
    gld_lds16(Bb + (long)(n0 + row) * ldb + (k0 + kc), lBw);
    gld_lds16(Bb + (long)(n0 + 64 + row) * ldb + (k0 + kc), lBw + 2048);
    __syncthreads();
    bf16x8 af[4], bfr[4];
#pragma unroll
    for (int i = 0; i < 4; ++i)
      af[i] = *(const bf16x8*)&lA[(wm + i * 16 + ml) * 32 + qd * 8];
#pragma unroll
    for (int j = 0; j < 4; ++j)
      bfr[j] = *(const bf16x8*)&lB[(wn + j * 16 + ml) * 32 + qd * 8];
#pragma unroll
    for (int i = 0; i < 4; ++i)
#pragma unroll
      for (int j = 0; j < 4; ++j)
        acc[i][j] = __builtin_amdgcn_mfma_f32_16x16x32_bf16(af[i], bfr[j], acc[i][j], 0, 0, 0);
    __syncthreads();
  }

  const long cb = bz * sC;
#pragma unroll
  for (int i = 0; i < 4; ++i) {
#pragma unroll
    for (int j = 0; j < 4; ++j) {
#pragma unroll
      for (int r = 0; r < 4; ++r) {
        int rr = m0 + wm + i * 16 + qd * 4 + r;   // C/D row = quad*4+reg (m89)
        int cc = n0 + wn + j * 16 + ml;           // C/D col = lane&15
        float v = acc[i][j][r] * alpha;
        if (BIASMODE == 1) v += bias[rr];
        if (BIASMODE == 2) v += bias[cc];
        long idx = (long)rr * N + cc;
        if (RESID) v += resid[bz * sR + idx];
        if (OUTF32) ((float*)C)[cb + idx] = v;
        else        ((u16*)C)[cb + idx] = f2b(v);
      }
    }
  }
}

// ---------------------------------------------------------------------------
// GroupNorm, f32 input [n][c][p] -> bf16 out TRANSPOSED to [n][p][c].
// ---------------------------------------------------------------------------
__global__ __launch_bounds__(256)
void groupnorm_f32(const float* __restrict__ x, const float* __restrict__ gamma,
                   const float* __restrict__ beta, u16* __restrict__ out)
{
  const int C = 512, HW = 1024;
  const int n = blockIdx.x >> 5, g = blockIdx.x & 31;
  const float* xg = x + ((long)n * C + g * 16) * HW;
  const int t = threadIdx.x;
  float s = 0.f, ss = 0.f;
  for (int ch = t; ch < 4096; ch += 256) {
    float4 u = *(const float4*)(xg + ch * 4);
    s += u.x + u.y + u.z + u.w;
    ss += u.x * u.x + u.y * u.y + u.z * u.z + u.w * u.w;
  }
#pragma unroll
  for (int off = 32; off > 0; off >>= 1) { s += __shfl_xor(s, off); ss += __shfl_xor(ss, off); }
  __shared__ float rs[4], rss[4];
  if ((t & 63) == 0) { rs[t >> 6] = s; rss[t >> 6] = ss; }
  __syncthreads();
  s  = rs[0] + rs[1] + rs[2] + rs[3];
  ss = rss[0] + rss[1] + rss[2] + rss[3];
  const float mu = s * (1.f / 16384.f);
  const float var = ss * (1.f / 16384.f) - mu * mu;
  const float rstd = rsqrtf(var + 1e-6f);
  float gm[16], bt[16];
#pragma unroll
  for (int i = 0; i < 16; ++i) {
    float ga = gamma[g * 16 + i];
    gm[i] = ga * rstd;
    bt[i] = beta[g * 16 + i] - mu * ga * rstd;
  }
  for (int p = t; p < 1024; p += 256) {
    alignas(16) u16 vals[16];
#pragma unroll
    for (int i = 0; i < 16; ++i)
      vals[i] = f2b(xg[(long)i * HW + p] * gm[i] + bt[i]);
    u16* dst = out + ((long)n * HW + p) * C + g * 16;
    *(uint4*)dst       = *(const uint4*)&vals[0];
    *(uint4*)(dst + 8) = *(const uint4*)&vals[8];
  }
}

// Same, bf16 input [n][c][p] -> bf16 out [n][p][c].
__global__ __launch_bounds__(256)
void groupnorm_bf16(const u16* __restrict__ x, const float* __restrict__ gamma,
                    const float* __restrict__ beta, u16* __restrict__ out)
{
  const int C = 512, HW = 1024;
  const int n = blockIdx.x >> 5, g = blockIdx.x & 31;
  const u16* xg = x + ((long)n * C + g * 16) * HW;
  const int t = threadIdx.x;
  float s = 0.f, ss = 0.f;
  for (int ch = t; ch < 2048; ch += 256) {
    uint4 u = *(const uint4*)(xg + ch * 8);
    uint32_t w[4] = {u.x, u.y, u.z, u.w};
#pragma unroll
    for (int k = 0; k < 4; ++k) {
      float f0 = __uint_as_float(w[k] << 16);
      float f1 = __uint_as_float(w[k] & 0xffff0000u);
      s += f0 + f1; ss += f0 * f0 + f1 * f1;
    }
  }
#pragma unroll
  for (int off = 32; off > 0; off >>= 1) { s += __shfl_xor(s, off); ss += __shfl_xor(ss, off); }
  __shared__ float rs[4], rss[4];
  if ((t & 63) == 0) { rs[t >> 6] = s; rss[t >> 6] = ss; }
  __syncthreads();
  s  = rs[0] + rs[1] + rs[2] + rs[3];
  ss = rss[0] + rss[1] + rss[2] + rss[3];
  const float mu = s * (1.f / 16384.f);
  const float var = ss * (1.f / 16384.f) - mu * mu;
  const float rstd = rsqrtf(var + 1e-6f);
  float gm[16], bt[16];
#pragma unroll
  for (int i = 0; i < 16; ++i) {
    float ga = gamma[g * 16 + i];
    gm[i] = ga * rstd;
    bt[i] = beta[g * 16 + i] - mu * ga * rstd;
  }
  for (int p = t; p < 1024; p += 256) {
    alignas(16) u16 vals[16];
#pragma unroll
    for (int i = 0; i < 16; ++i)
      vals[i] = f2b(b2f(xg[(long)i * HW + p]) * gm[i] + bt[i]);
    u16* dst = out + ((long)n * HW + p) * C + g * 16;
    *(uint4*)dst       = *(const uint4*)&vals[0];
    *(uint4*)(dst + 8) = *(const uint4*)&vals[8];
  }
}

// ---------------------------------------------------------------------------
// In-place softmax over rows of 1024 bf16. One block per row (20480 rows).
// ---------------------------------------------------------------------------
__global__ __launch_bounds__(256)
void softmax1024(u16* __restrict__ data)
{
  u16* row = data + (long)blockIdx.x * 1024;
  const int t = threadIdx.x;
  uint2 u = *(const uint2*)(row + t * 4);
  float v[4];
  v[0] = __uint_as_float(u.x << 16); v[1] = __uint_as_float(u.x & 0xffff0000u);
  v[2] = __uint_as_float(u.y << 16); v[3] = __uint_as_float(u.y & 0xffff0000u);
  float mx = fmaxf(fmaxf(v[0], v[1]), fmaxf(v[2], v[3]));
#pragma unroll
  for (int off = 32; off > 0; off >>= 1) mx = fmaxf(mx, __shfl_xor(mx, off));
  __shared__ float red[8];
  if ((t & 63) == 0) red[t >> 6] = mx;
  __syncthreads();
  mx = fmaxf(fmaxf(red[0], red[1]), fmaxf(red[2], red[3]));
  float e[4]; float s = 0.f;
#pragma unroll
  for (int k = 0; k < 4; ++k) { e[k] = __expf(v[k] - mx); s += e[k]; }
#pragma unroll
  for (int off = 32; off > 0; off >>= 1) s += __shfl_xor(s, off);
  if ((t & 63) == 0) red[4 + (t >> 6)] = s;
  __syncthreads();
  s = red[4] + red[5] + red[6] + red[7];
  float inv = 1.f / s;
  uint2 o;
  o.x = (uint32_t)f2b(e[0] * inv) | ((uint32_t)f2b(e[1] * inv) << 16);
  o.y = (uint32_t)f2b(e[2] * inv) | ((uint32_t)f2b(e[3] * inv) << 16);
  *(uint2*)(row + t * 4) = o;
}

// ---------------------------------------------------------------------------
// Temporal attention v3: one WAVE per pixel (b,p). qkv fused [20480][1536]
// (row = q(512)||k(512)||v(512) for frame n=b*5+f, pixel p). Lane l owns
// channels 8l..8l+7: bf16x8 loads, coalesced, no LDS. 25 scores butterfly-
// reduced via __shfl_xor; softmax replicated; PV in registers; out [20480][512].
// Grid: 1024 blocks x 256 (4 waves = 4 pixels per block).
// ---------------------------------------------------------------------------
__global__ __launch_bounds__(256)
void temporal_attn(const u16* __restrict__ qkv, u16* __restrict__ htp)
{
  const int t = threadIdx.x;
  const int wv = t >> 6, lane = t & 63;
  const int pix = blockIdx.x * 4 + wv;      // 0..4095 = (b, p)
  const int b = pix >> 10, p = pix & 1023;
  const long fs = 1024l * 1536;             // frame stride in qkv
  const long rowbase = ((long)b * 5 * 1024 + p) * 1536 + lane * 8;

  float qf[5][8], kf[5][8];
#pragma unroll
  for (int f = 0; f < 5; ++f) {
    bf16x8 qv = *(const bf16x8*)(qkv + rowbase + f * fs);
    bf16x8 kv = *(const bf16x8*)(qkv + rowbase + f * fs + 512);
#pragma unroll
    for (int u = 0; u < 8; ++u) { qf[f][u] = b2f((u16)qv[u]); kf[f][u] = b2f((u16)kv[u]); }
  }
  float sc[25];
#pragma unroll
  for (int i = 0; i < 5; ++i)
#pragma unroll
    for (int j = 0; j < 5; ++j) {
      float a = 0.f;
#pragma unroll
      for (int u = 0; u < 8; ++u) a += qf[i][u] * kf[j][u];
      sc[i * 5 + j] = a;
    }
#pragma unroll
  for (int m = 1; m < 64; m <<= 1)
#pragma unroll
    for (int s = 0; s < 25; ++s) sc[s] += __shfl_xor(sc[s], m);

  const float scale = 0.04419417382415922f;  // 512^-0.5
  float att[5][5];
#pragma unroll
  for (int i = 0; i < 5; ++i) {
    float m = sc[i * 5];
#pragma unroll
    for (int j = 1; j < 5; ++j) m = fmaxf(m, sc[i * 5 + j]);
    float ssum = 0.f;
#pragma unroll
    for (int j = 0; j < 5; ++j) { att[i][j] = __expf((sc[i * 5 + j] - m) * scale); ssum += att[i][j]; }
    float inv = 1.f / ssum;
#pragma unroll
    for (int j = 0; j < 5; ++j) att[i][j] *= inv;
  }

  float of[5][8];
#pragma unroll
  for (int i = 0; i < 5; ++i)
#pragma unroll
    for (int u = 0; u < 8; ++u) of[i][u] = 0.f;
#pragma unroll
  for (int s = 0; s < 5; ++s) {
    bf16x8 vvv = *(const bf16x8*)(qkv + rowbase + s * fs + 1024);
#pragma unroll
    for (int u = 0; u < 8; ++u) {
      float vf = b2f((u16)vvv[u]);
#pragma unroll
      for (int i = 0; i < 5; ++i) of[i][u] += att[i][s] * vf;
    }
  }
  const long obase = ((long)b * 5 * 1024 + p) * 512 + lane * 8;
#pragma unroll
  for (int i = 0; i < 5; ++i) {
    alignas(16) u16 ob[8];
#pragma unroll
    for (int u = 0; u < 8; ++u) ob[u] = f2b(of[i][u]);
    *(uint4*)(htp + obase + i * 1024 * 512) = *(const uint4*)ob;
  }
}

// ---------------------------------------------------------------------------
extern "C" void kernel_launch(void* const* d_in, const int* in_sizes, int n_in,
                              void* d_out, int out_size, void* d_ws, size_t ws_size,
                              hipStream_t stream)
{
  const float* x   = (const float*)d_in[0];
  const float* wq  = (const float*)d_in[1];
  const float* bq  = (const float*)d_in[2];
  const float* wk  = (const float*)d_in[3];
  const float* bk  = (const float*)d_in[4];
  const float* wv  = (const float*)d_in[5];
  const float* bv  = (const float*)d_in[6];
  const float* wo  = (const float*)d_in[7];
  const float* bo  = (const float*)d_in[8];
  const float* wqt = (const float*)d_in[9];
  const float* bqt = (const float*)d_in[10];
  const float* wkt = (const float*)d_in[11];
  const float* bkt = (const float*)d_in[12];
  const float* wvt = (const float*)d_in[13];
  const float* bvt = (const float*)d_in[14];
  const float* wot = (const float*)d_in[15];
  const float* bot = (const float*)d_in[16];
  const float* gs  = (const float*)d_in[17];
  const float* bs  = (const float*)d_in[18];
  const float* gt  = (const float*)d_in[19];
  const float* btt = (const float*)d_in[20];

  // ws_size = 256 MiB (measured: harness poison fill writes 2.684e8 B).
  // Slots W0..W7 (8 x 20 MB), weights Wt (4 MB), packed biases Bf (16 KB).
  const long U = 20l * 1024 * 512;          // elements per slot
  u16* W0 = (u16*)d_ws;
  u16* W1 = W0 + U;                          // W1..W3 contiguous 60 MB (qkv_t)
  u16* W3 = W0 + 3 * U;
  u16* W4 = W0 + 4 * U;                      // W4..W5 contiguous 40 MB (scores)
  u16* W6 = W0 + 6 * U;
  u16* W7 = W0 + 7 * U;
  u16* Wt = W0 + 8 * U;                      // 8 x 262144 bf16 weights
  float* Bf = (float*)(Wt + 8 * 262144);     // 8 x 512 f32 biases
  u16* wv_b  = Wt + 2 * 262144;
  u16* wo_b  = Wt + 3 * 262144;
  u16* wqt_b = Wt + 4 * 262144;
  u16* wot_b = Wt + 7 * 262144;

  const long S  = 524288;                   // 1024*512 per-image stride
  const long S2 = 1048576;                  // 1024*1024 per-image stride
  const float scale = 0.04419417382415922f; // 512^-0.5
  dim3 blk(256);

  convert_w8<<<1024, blk, 0, stream>>>(wq, wk, wv, wo, wqt, wkt, wvt, wot, Wt);
  pack_biases<<<1, blk, 0, stream>>>(bq, bk, bv, bo, bqt, bkt, bvt, bot, Bf);

  // hn = GroupNorm_s(x) -> W0 [n][p][c] (= [20480][512] row-major)
  groupnorm_f32<<<640, blk, 0, stream>>>(x, gs, bs, W0);
  // qk fused: M=20480, N=1024 (wq||wk), K=512 -> W1W2 [20480][1024]
  gemm_bt<0, 2, 0><<<dim3(8, 160, 1), blk, 0, stream>>>(
      W0, 0, 512, Wt, 0, 512, W1, 0, Bf, nullptr, 0, 1024, 512, 1.f);
  // v: batched z=20, M=o(512), N=p(1024): A=wv_b, Bt=hn -> W3 [20][c][p]
  gemm_bt<0, 1, 0><<<dim3(8, 4, 20), blk, 0, stream>>>(
      wv_b, 0, 512, W0, S, 512, W3, S, Bf + 1024, nullptr, 0, 1024, 512, 1.f);
  // scores = scale * q.k^T: z=20, A=q (W1, ld 1024), Bt=k (W1+512) -> W4W5
  gemm_bt<0, 0, 0><<<dim3(8, 8, 20), blk, 0, stream>>>(
      W1, S2, 1024, W1 + 512, S2, 1024, W4, S2, nullptr, nullptr, 0, 1024, 512, scale);
  softmax1024<<<20480, blk, 0, stream>>>(W4);
  // hsp^T = att . v^T: z=20, M=pq, N=c(512), K=pk(1024) -> W0 [p][c] (hn dead)
  gemm_bt<0, 0, 0><<<dim3(4, 8, 20), blk, 0, stream>>>(
      W4, S2, 1024, W3, S, 1024, W0, S, nullptr, nullptr, 0, 512, 1024, 1.f);
  // spatio = x + wo.hsp + bo: z=20 -> W6 [c][p] bf16
  gemm_bt<0, 1, 1><<<dim3(8, 4, 20), blk, 0, stream>>>(
      wo_b, 0, 512, W0, S, 512, W6, S, Bf + 1536, x, S, 1024, 512, 1.f);
  // hn_t = GroupNorm_t(spatio) -> W7 [n][p][c]
  groupnorm_bf16<<<640, blk, 0, stream>>>(W6, gt, btt, W7);
  // qkv_t fused: M=20480, N=1536 (wqt||wkt||wvt), K=512 -> W1..W3 [20480][1536]
  gemm_bt<0, 2, 0><<<dim3(12, 160, 1), blk, 0, stream>>>(
      W7, 0, 512, wqt_b, 0, 512, W1, 0, Bf + 2048, nullptr, 0, 1536, 512, 1.f);
  // per-pixel 5x5 temporal attention -> W0 htp [20480][512]
  temporal_attn<<<1024, blk, 0, stream>>>(W1, W0);
  // out = x + wot.htp + bot -> d_out f32, z=20
  gemm_bt<1, 1, 1><<<dim3(8, 4, 20), blk, 0, stream>>>(
      wot_b, 0, 512, W0, S, 512, (float*)d_out, S, Bf + 3584, x, S, 1024, 512, 1.f);
}

// Round 7
// 474.880 us; speedup vs baseline: 1.2435x; 1.0070x over previous
//
#include <hip/hip_runtime.h>
#include <hip/hip_bf16.h>
#include <stdint.h>

typedef unsigned short u16;
typedef __attribute__((ext_vector_type(8))) short bf16x8;
typedef __attribute__((ext_vector_type(4))) float f32x4;

#define DI __device__ __forceinline__

DI float b2f(u16 u) { return __uint_as_float(((uint32_t)u) << 16); }
DI u16 f2b(float f) {
  uint32_t u = __float_as_uint(f);
  u += 0x7fff + ((u >> 16) & 1);   // RNE
  return (u16)(u >> 16);
}

DI void gld_lds16(const u16* g, u16* l) {
  __builtin_amdgcn_global_load_lds((const __attribute__((address_space(1))) void*)g,
                                   (__attribute__((address_space(3))) void*)l,
                                   16, 0, 0);
}

// ---------------------------------------------------------------------------
// Setup: convert 8 weight matrices (512x512 f32) to bf16 (concatenated, order
// wq wk wv wo wqt wkt wvt wot) + pack 8 bias vectors into Bf.
// Blocks 0..1023: weights. Blocks 1024..1031: biases.
// ---------------------------------------------------------------------------
__global__ __launch_bounds__(256)
void setup_wb(const float* __restrict__ w0, const float* __restrict__ w1,
              const float* __restrict__ w2, const float* __restrict__ w3,
              const float* __restrict__ w4, const float* __restrict__ w5,
              const float* __restrict__ w6, const float* __restrict__ w7,
              const float* __restrict__ b0, const float* __restrict__ b1,
              const float* __restrict__ b2, const float* __restrict__ b3,
              const float* __restrict__ b4, const float* __restrict__ b5,
              const float* __restrict__ b6, const float* __restrict__ b7,
              u16* __restrict__ dst, float* __restrict__ bdst)
{
  if (blockIdx.x >= 1024) {
    const float* bs[8] = {b0, b1, b2, b3, b4, b5, b6, b7};
    const int a = blockIdx.x - 1024;
    const int i = threadIdx.x;
    bdst[a * 512 + i] = bs[a][i];
    bdst[a * 512 + i + 256] = bs[a][i + 256];
    return;
  }
  const float* srcs[8] = {w0, w1, w2, w3, w4, w5, w6, w7};
  const int mat = blockIdx.x >> 7;                 // 128 blocks per matrix
  const int i = (((blockIdx.x & 127) << 8) + threadIdx.x) * 8;
  const float* s = srcs[mat];
  float4 a = *(const float4*)(s + i);
  float4 b = *(const float4*)(s + i + 4);
  alignas(16) u16 v[8] = {f2b(a.x), f2b(a.y), f2b(a.z), f2b(a.w),
                          f2b(b.x), f2b(b.y), f2b(b.z), f2b(b.w)};
  *(uint4*)(dst + (long)mat * 262144 + i) = *(const uint4*)v;
}

// ---------------------------------------------------------------------------
// Batched GEMM: out[m][n] = alpha * sum_k A[m*lda+k]*Bt[n*ldb+k]  (+bias,+resid)
// A,Bt bf16; bias/resid f32; out bf16 or f32 (OUTF32). ldC = N.
// BM=BN=128, BK=32, 256 threads (4 waves as 2x2 of 64x64), 16x16x32 bf16 MFMA.
// global_load_lds width=16 staging with XOR-swizzled k-chunks:
//   LDS slot s of row r holds global chunk g = s ^ ((r>>1)&3)
// so quad reads spread over 8 bank-starts (2-way aliasing = free, m136)
// instead of 2 (8-way conflict). Swizzle is loop-invariant: zero K-loop cost.
// BIASMODE: 0 none, 1 bias[row], 2 bias[col].
// ---------------------------------------------------------------------------
template<int OUTF32, int BIASMODE, int RESID>
__global__ __launch_bounds__(256)
void gemm_bt(const u16* __restrict__ A, long sA, long lda,
             const u16* __restrict__ B, long sB, long ldb,
             void* __restrict__ C, long sC,
             const float* __restrict__ bias,
             const float* __restrict__ resid, long sR,
             int N, int K, float alpha)
{
  __shared__ u16 lA[128 * 32];
  __shared__ u16 lB[128 * 32];
  const int t = threadIdx.x;
  const int lane = t & 63;
  const int m0 = blockIdx.y * 128, n0 = blockIdx.x * 128;
  const long bz = blockIdx.z;
  const u16* Ab = A + bz * sA;
  const u16* Bb = B + bz * sB;

  const int row = t >> 2;          // 0..63
  // staged global k-chunk for this lane (slot = t&3): g = slot ^ ((row>>1)&3)
  const int kc  = (((t & 3) ^ ((t >> 3) & 3)) << 3);
  const int wid = t >> 6;
  u16* lAw = lA + wid * 512;       // wave-uniform LDS base; HW adds lane*16B
  u16* lBw = lB + wid * 512;

  f32x4 acc[4][4];
#pragma unroll
  for (int i = 0; i < 4; ++i)
#pragma unroll
    for (int j = 0; j < 4; ++j) acc[i][j] = (f32x4){0.f, 0.f, 0.f, 0.f};

  const int ml = lane & 15, qd = lane >> 4;
  const int koff = ((qd ^ ((ml >> 1) & 3)) << 3);  // swizzled read offset (elems)
  const int wm = (wid >> 1) * 64, wn = (wid & 1) * 64;

  for (int k0 = 0; k0 < K; k0 += 32) {
    gld_lds16(Ab + (long)(m0 + row) * lda + (k0 + kc), lAw);
    gld_lds16(Ab + (long)(m0 + 64 + row) * lda + (k0 + kc), lAw + 2048);
    gld_lds16(Bb + (long)(n0 + row) * ldb + (k0 + kc), lBw);
    gld_lds16(Bb + (long)(n0 + 64 + row) * ldb + (k0 + kc), lBw + 2048);
    __syncthreads();
    bf16x8 af[4], bfr[4];
#pragma unroll
    for (int i = 0; i < 4; ++i)
      af[i] = *(const bf16x8*)&lA[(wm + i * 16 + ml) * 32 + koff];
#pragma unroll
    for (int j = 0; j < 4; ++j)
      bfr[j] = *(const bf16x8*)&lB[(wn + j * 16 + ml) * 32 + koff];
#pragma unroll
    for (int i = 0; i < 4; ++i)
#pragma unroll
      for (int j = 0; j < 4; ++j)
        acc[i][j] = __builtin_amdgcn_mfma_f32_16x16x32_bf16(af[i], bfr[j], acc[i][j], 0, 0, 0);
    __syncthreads();
  }

  const long cb = bz * sC;
#pragma unroll
  for (int i = 0; i < 4; ++i) {
#pragma unroll
    for (int j = 0; j < 4; ++j) {
#pragma unroll
      for (int r = 0; r < 4; ++r) {
        int rr = m0 + wm + i * 16 + qd * 4 + r;   // C/D row = quad*4+reg (m89)
        int cc = n0 + wn + j * 16 + ml;           // C/D col = lane&15
        float v = acc[i][j][r] * alpha;
        if (BIASMODE == 1) v += bias[rr];
        if (BIASMODE == 2) v += bias[cc];
        long idx = (long)rr * N + cc;
        if (RESID) v += resid[bz * sR + idx];
        if (OUTF32) ((float*)C)[cb + idx] = v;
        else        ((u16*)C)[cb + idx] = f2b(v);
      }
    }
  }
}

// ---------------------------------------------------------------------------
// GroupNorm, f32 input [n][c][p] -> bf16 out TRANSPOSED to [n][p][c].
// ---------------------------------------------------------------------------
__global__ __launch_bounds__(256)
void groupnorm_f32(const float* __restrict__ x, const float* __restrict__ gamma,
                   const float* __restrict__ beta, u16* __restrict__ out)
{
  const int C = 512, HW = 1024;
  const int n = blockIdx.x >> 5, g = blockIdx.x & 31;
  const float* xg = x + ((long)n * C + g * 16) * HW;
  const int t = threadIdx.x;
  float s = 0.f, ss = 0.f;
  for (int ch = t; ch < 4096; ch += 256) {
    float4 u = *(const float4*)(xg + ch * 4);
    s += u.x + u.y + u.z + u.w;
    ss += u.x * u.x + u.y * u.y + u.z * u.z + u.w * u.w;
  }
#pragma unroll
  for (int off = 32; off > 0; off >>= 1) { s += __shfl_xor(s, off); ss += __shfl_xor(ss, off); }
  __shared__ float rs[4], rss[4];
  if ((t & 63) == 0) { rs[t >> 6] = s; rss[t >> 6] = ss; }
  __syncthreads();
  s  = rs[0] + rs[1] + rs[2] + rs[3];
  ss = rss[0] + rss[1] + rss[2] + rss[3];
  const float mu = s * (1.f / 16384.f);
  const float var = ss * (1.f / 16384.f) - mu * mu;
  const float rstd = rsqrtf(var + 1e-6f);
  float gm[16], bt[16];
#pragma unroll
  for (int i = 0; i < 16; ++i) {
    float ga = gamma[g * 16 + i];
    gm[i] = ga * rstd;
    bt[i] = beta[g * 16 + i] - mu * ga * rstd;
  }
  for (int p = t; p < 1024; p += 256) {
    alignas(16) u16 vals[16];
#pragma unroll
    for (int i = 0; i < 16; ++i)
      vals[i] = f2b(xg[(long)i * HW + p] * gm[i] + bt[i]);
    u16* dst = out + ((long)n * HW + p) * C + g * 16;
    *(uint4*)dst       = *(const uint4*)&vals[0];
    *(uint4*)(dst + 8) = *(const uint4*)&vals[8];
  }
}

// Same, bf16 input [n][c][p] -> bf16 out [n][p][c].
__global__ __launch_bounds__(256)
void groupnorm_bf16(const u16* __restrict__ x, const float* __restrict__ gamma,
                    const float* __restrict__ beta, u16* __restrict__ out)
{
  const int C = 512, HW = 1024;
  const int n = blockIdx.x >> 5, g = blockIdx.x & 31;
  const u16* xg = x + ((long)n * C + g * 16) * HW;
  const int t = threadIdx.x;
  float s = 0.f, ss = 0.f;
  for (int ch = t; ch < 2048; ch += 256) {
    uint4 u = *(const uint4*)(xg + ch * 8);
    uint32_t w[4] = {u.x, u.y, u.z, u.w};
#pragma unroll
    for (int k = 0; k < 4; ++k) {
      float f0 = __uint_as_float(w[k] << 16);
      float f1 = __uint_as_float(w[k] & 0xffff0000u);
      s += f0 + f1; ss += f0 * f0 + f1 * f1;
    }
  }
#pragma unroll
  for (int off = 32; off > 0; off >>= 1) { s += __shfl_xor(s, off); ss += __shfl_xor(ss, off); }
  __shared__ float rs[4], rss[4];
  if ((t & 63) == 0) { rs[t >> 6] = s; rss[t >> 6] = ss; }
  __syncthreads();
  s  = rs[0] + rs[1] + rs[2] + rs[3];
  ss = rss[0] + rss[1] + rss[2] + rss[3];
  const float mu = s * (1.f / 16384.f);
  const float var = ss * (1.f / 16384.f) - mu * mu;
  const float rstd = rsqrtf(var + 1e-6f);
  float gm[16], bt[16];
#pragma unroll
  for (int i = 0; i < 16; ++i) {
    float ga = gamma[g * 16 + i];
    gm[i] = ga * rstd;
    bt[i] = beta[g * 16 + i] - mu * ga * rstd;
  }
  for (int p = t; p < 1024; p += 256) {
    alignas(16) u16 vals[16];
#pragma unroll
    for (int i = 0; i < 16; ++i)
      vals[i] = f2b(b2f(xg[(long)i * HW + p]) * gm[i] + bt[i]);
    u16* dst = out + ((long)n * HW + p) * C + g * 16;
    *(uint4*)dst       = *(const uint4*)&vals[0];
    *(uint4*)(dst + 8) = *(const uint4*)&vals[8];
  }
}

// ---------------------------------------------------------------------------
// In-place softmax over rows of 1024 bf16. One block per row (20480 rows).
// ---------------------------------------------------------------------------
__global__ __launch_bounds__(256)
void softmax1024(u16* __restrict__ data)
{
  u16* row = data + (long)blockIdx.x * 1024;
  const int t = threadIdx.x;
  uint2 u = *(const uint2*)(row + t * 4);
  float v[4];
  v[0] = __uint_as_float(u.x << 16); v[1] = __uint_as_float(u.x & 0xffff0000u);
  v[2] = __uint_as_float(u.y << 16); v[3] = __uint_as_float(u.y & 0xffff0000u);
  float mx = fmaxf(fmaxf(v[0], v[1]), fmaxf(v[2], v[3]));
#pragma unroll
  for (int off = 32; off > 0; off >>= 1) mx = fmaxf(mx, __shfl_xor(mx, off));
  __shared__ float red[8];
  if ((t & 63) == 0) red[t >> 6] = mx;
  __syncthreads();
  mx = fmaxf(fmaxf(red[0], red[1]), fmaxf(red[2], red[3]));
  float e[4]; float s = 0.f;
#pragma unroll
  for (int k = 0; k < 4; ++k) { e[k] = __expf(v[k] - mx); s += e[k]; }
#pragma unroll
  for (int off = 32; off > 0; off >>= 1) s += __shfl_xor(s, off);
  if ((t & 63) == 0) red[4 + (t >> 6)] = s;
  __syncthreads();
  s = red[4] + red[5] + red[6] + red[7];
  float inv = 1.f / s;
  uint2 o;
  o.x = (uint32_t)f2b(e[0] * inv) | ((uint32_t)f2b(e[1] * inv) << 16);
  o.y = (uint32_t)f2b(e[2] * inv) | ((uint32_t)f2b(e[3] * inv) << 16);
  *(uint2*)(row + t * 4) = o;
}

// ---------------------------------------------------------------------------
// Temporal attention: one WAVE per pixel (b,p). qkv fused [20480][1536]
// (row = q||k||v per frame/pixel). Lane l owns channels 8l..8l+7.
// ---------------------------------------------------------------------------
__global__ __launch_bounds__(256)
void temporal_attn(const u16* __restrict__ qkv, u16* __restrict__ htp)
{
  const int t = threadIdx.x;
  const int wv = t >> 6, lane = t & 63;
  const int pix = blockIdx.x * 4 + wv;      // 0..4095 = (b, p)
  const int b = pix >> 10, p = pix & 1023;
  const long fs = 1024l * 1536;             // frame stride in qkv
  const long rowbase = ((long)b * 5 * 1024 + p) * 1536 + lane * 8;

  float qf[5][8], kf[5][8];
#pragma unroll
  for (int f = 0; f < 5; ++f) {
    bf16x8 qv = *(const bf16x8*)(qkv + rowbase + f * fs);
    bf16x8 kv = *(const bf16x8*)(qkv + rowbase + f * fs + 512);
#pragma unroll
    for (int u = 0; u < 8; ++u) { qf[f][u] = b2f((u16)qv[u]); kf[f][u] = b2f((u16)kv[u]); }
  }
  float sc[25];
#pragma unroll
  for (int i = 0; i < 5; ++i)
#pragma unroll
    for (int j = 0; j < 5; ++j) {
      float a = 0.f;
#pragma unroll
      for (int u = 0; u < 8; ++u) a += qf[i][u] * kf[j][u];
      sc[i * 5 + j] = a;
    }
#pragma unroll
  for (int m = 1; m < 64; m <<= 1)
#pragma unroll
    for (int s = 0; s < 25; ++s) sc[s] += __shfl_xor(sc[s], m);

  const float scale = 0.04419417382415922f;  // 512^-0.5
  float att[5][5];
#pragma unroll
  for (int i = 0; i < 5; ++i) {
    float m = sc[i * 5];
#pragma unroll
    for (int j = 1; j < 5; ++j) m = fmaxf(m, sc[i * 5 + j]);
    float ssum = 0.f;
#pragma unroll
    for (int j = 0; j < 5; ++j) { att[i][j] = __expf((sc[i * 5 + j] - m) * scale); ssum += att[i][j]; }
    float inv = 1.f / ssum;
#pragma unroll
    for (int j = 0; j < 5; ++j) att[i][j] *= inv;
  }

  float of[5][8];
#pragma unroll
  for (int i = 0; i < 5; ++i)
#pragma unroll
    for (int u = 0; u < 8; ++u) of[i][u] = 0.f;
#pragma unroll
  for (int s = 0; s < 5; ++s) {
    bf16x8 vvv = *(const bf16x8*)(qkv + rowbase + s * fs + 1024);
#pragma unroll
    for (int u = 0; u < 8; ++u) {
      float vf = b2f((u16)vvv[u]);
#pragma unroll
      for (int i = 0; i < 5; ++i) of[i][u] += att[i][s] * vf;
    }
  }
  const long obase = ((long)b * 5 * 1024 + p) * 512 + lane * 8;
#pragma unroll
  for (int i = 0; i < 5; ++i) {
    alignas(16) u16 ob[8];
#pragma unroll
    for (int u = 0; u < 8; ++u) ob[u] = f2b(of[i][u]);
    *(uint4*)(htp + obase + i * 1024 * 512) = *(const uint4*)ob;
  }
}

// ---------------------------------------------------------------------------
extern "C" void kernel_launch(void* const* d_in, const int* in_sizes, int n_in,
                              void* d_out, int out_size, void* d_ws, size_t ws_size,
                              hipStream_t stream)
{
  const float* x   = (const float*)d_in[0];
  const float* wq  = (const float*)d_in[1];
  const float* bq  = (const float*)d_in[2];
  const float* wk  = (const float*)d_in[3];
  const float* bk  = (const float*)d_in[4];
  const float* wv  = (const float*)d_in[5];
  const float* bv  = (const float*)d_in[6];
  const float* wo  = (const float*)d_in[7];
  const float* bo  = (const float*)d_in[8];
  const float* wqt = (const float*)d_in[9];
  const float* bqt = (const float*)d_in[10];
  const float* wkt = (const float*)d_in[11];
  const float* bkt = (const float*)d_in[12];
  const float* wvt = (const float*)d_in[13];
  const float* bvt = (const float*)d_in[14];
  const float* wot = (const float*)d_in[15];
  const float* bot = (const float*)d_in[16];
  const float* gs  = (const float*)d_in[17];
  const float* bs  = (const float*)d_in[18];
  const float* gt  = (const float*)d_in[19];
  const float* btt = (const float*)d_in[20];

  // ws = 256 MiB. Slots W0..W7 (8 x 20 MB), weights Wt (4 MB), biases Bf.
  const long U = 20l * 1024 * 512;          // elements per slot
  u16* W0 = (u16*)d_ws;
  u16* W1 = W0 + U;                          // W1..W3 contiguous 60 MB (qkv_t)
  u16* W3 = W0 + 3 * U;
  u16* W4 = W0 + 4 * U;                      // W4..W5 contiguous 40 MB (scores)
  u16* W6 = W0 + 6 * U;
  u16* W7 = W0 + 7 * U;
  u16* Wt = W0 + 8 * U;                      // 8 x 262144 bf16 weights
  float* Bf = (float*)(Wt + 8 * 262144);     // 8 x 512 f32 biases
  u16* wv_b  = Wt + 2 * 262144;
  u16* wo_b  = Wt + 3 * 262144;
  u16* wqt_b = Wt + 4 * 262144;
  u16* wot_b = Wt + 7 * 262144;

  const long S  = 524288;                   // 1024*512 per-image stride
  const long S2 = 1048576;                  // 1024*1024 per-image stride
  const float scale = 0.04419417382415922f; // 512^-0.5
  dim3 blk(256);

  setup_wb<<<1032, blk, 0, stream>>>(wq, wk, wv, wo, wqt, wkt, wvt, wot,
                                     bq, bk, bv, bo, bqt, bkt, bvt, bot, Wt, Bf);

  // hn = GroupNorm_s(x) -> W0 [n][p][c] (= [20480][512] row-major)
  groupnorm_f32<<<640, blk, 0, stream>>>(x, gs, bs, W0);
  // qk fused: M=20480, N=1024 (wq||wk), K=512 -> W1W2 [20480][1024]
  gemm_bt<0, 2, 0><<<dim3(8, 160, 1), blk, 0, stream>>>(
      W0, 0, 512, Wt, 0, 512, W1, 0, Bf, nullptr, 0, 1024, 512, 1.f);
  // v: batched z=20, M=o(512), N=p(1024): A=wv_b, Bt=hn -> W3 [20][c][p]
  gemm_bt<0, 1, 0><<<dim3(8, 4, 20), blk, 0, stream>>>(
      wv_b, 0, 512, W0, S, 512, W3, S, Bf + 1024, nullptr, 0, 1024, 512, 1.f);
  // scores = scale * q.k^T: z=20, A=q (W1, ld 1024), Bt=k (W1+512) -> W4W5
  gemm_bt<0, 0, 0><<<dim3(8, 8, 20), blk, 0, stream>>>(
      W1, S2, 1024, W1 + 512, S2, 1024, W4, S2, nullptr, nullptr, 0, 1024, 512, scale);
  softmax1024<<<20480, blk, 0, stream>>>(W4);
  // hsp^T = att . v^T: z=20, M=pq, N=c(512), K=pk(1024) -> W0 [p][c] (hn dead)
  gemm_bt<0, 0, 0><<<dim3(4, 8, 20), blk, 0, stream>>>(
      W4, S2, 1024, W3, S, 1024, W0, S, nullptr, nullptr, 0, 512, 1024, 1.f);
  // spatio = x + wo.hsp + bo: z=20 -> W6 [c][p] bf16
  gemm_bt<0, 1, 1><<<dim3(8, 4, 20), blk, 0, stream>>>(
      wo_b, 0, 512, W0, S, 512, W6, S, Bf + 1536, x, S, 1024, 512, 1.f);
  // hn_t = GroupNorm_t(spatio) -> W7 [n][p][c]
  groupnorm_bf16<<<640, blk, 0, stream>>>(W6, gt, btt, W7);
  // qkv_t fused: M=20480, N=1536 (wqt||wkt||wvt), K=512 -> W1..W3 [20480][1536]
  gemm_bt<0, 2, 0><<<dim3(12, 160, 1), blk, 0, stream>>>(
      W7, 0, 512, wqt_b, 0, 512, W1, 0, Bf + 2048, nullptr, 0, 1536, 512, 1.f);
  // per-pixel 5x5 temporal attention -> W0 htp [20480][512]
  temporal_attn<<<1024, blk, 0, stream>>>(W1, W0);
  // out = x + wot.htp + bot -> d_out f32, z=20
  gemm_bt<1, 1, 1><<<dim3(8, 4, 20), blk, 0, stream>>>(
      wot_b, 0, 512, W0, S, 512, (float*)d_out, S, Bf + 3584, x, S, 1024, 512, 1.f);
}

// Round 8
// 447.228 us; speedup vs baseline: 1.3204x; 1.0618x over previous
//
#include <hip/hip_runtime.h>
#include <hip/hip_bf16.h>
#include <stdint.h>

typedef unsigned short u16;
typedef __attribute__((ext_vector_type(8))) short bf16x8;
typedef __attribute__((ext_vector_type(4))) float f32x4;

#define DI __device__ __forceinline__

DI float b2f(u16 u) { return __uint_as_float(((uint32_t)u) << 16); }
DI u16 f2b(float f) {
  uint32_t u = __float_as_uint(f);
  u += 0x7fff + ((u >> 16) & 1);   // RNE
  return (u16)(u >> 16);
}

DI void gld_lds16(const u16* g, u16* l) {
  __builtin_amdgcn_global_load_lds((const __attribute__((address_space(1))) void*)g,
                                   (__attribute__((address_space(3))) void*)l,
                                   16, 0, 0);
}

// ---------------------------------------------------------------------------
// Setup: convert 8 weight matrices (512x512 f32) to bf16 + pack 8 biases.
// ---------------------------------------------------------------------------
__global__ __launch_bounds__(256)
void setup_wb(const float* __restrict__ w0, const float* __restrict__ w1,
              const float* __restrict__ w2, const float* __restrict__ w3,
              const float* __restrict__ w4, const float* __restrict__ w5,
              const float* __restrict__ w6, const float* __restrict__ w7,
              const float* __restrict__ b0, const float* __restrict__ b1,
              const float* __restrict__ b2, const float* __restrict__ b3,
              const float* __restrict__ b4, const float* __restrict__ b5,
              const float* __restrict__ b6, const float* __restrict__ b7,
              u16* __restrict__ dst, float* __restrict__ bdst)
{
  if (blockIdx.x >= 1024) {
    const float* bs[8] = {b0, b1, b2, b3, b4, b5, b6, b7};
    const int a = blockIdx.x - 1024;
    const int i = threadIdx.x;
    bdst[a * 512 + i] = bs[a][i];
    bdst[a * 512 + i + 256] = bs[a][i + 256];
    return;
  }
  const float* srcs[8] = {w0, w1, w2, w3, w4, w5, w6, w7};
  const int mat = blockIdx.x >> 7;
  const int i = (((blockIdx.x & 127) << 8) + threadIdx.x) * 8;
  const float* s = srcs[mat];
  float4 a = *(const float4*)(s + i);
  float4 b = *(const float4*)(s + i + 4);
  alignas(16) u16 v[8] = {f2b(a.x), f2b(a.y), f2b(a.z), f2b(a.w),
                          f2b(b.x), f2b(b.y), f2b(b.z), f2b(b.w)};
  *(uint4*)(dst + (long)mat * 262144 + i) = *(const uint4*)v;
}

// ---------------------------------------------------------------------------
// Batched GEMM: out[m][n] = alpha * sum_k A[m*lda+k]*Bt[n*ldb+k]  (+bias,+resid)
// BM=BN=128, BK=64, 256 threads (4 waves as 2x2 of 64x64), 16x16x32 bf16 MFMA.
// - XCD-aware block remap: bid&7 = XCD proxy; each XCD gets a contiguous
//   y-strip range so the A-panel stays resident in that XCD's private L2.
// - BK=64: 32 MFMA per barrier (vs 16) — halves the vmcnt(0)+barrier drains.
// - XOR-swizzled LDS chunks: row r slot s holds global chunk s ^ (r&7);
//   quad reads spread over 8 bank-starts -> 2-way aliasing = free (m136).
// BIASMODE: 0 none, 1 bias[row], 2 bias[col].
// ---------------------------------------------------------------------------
template<int OUTF32, int BIASMODE, int RESID>
__global__ __launch_bounds__(256)
void gemm_bt(const u16* __restrict__ A, long sA, long lda,
             const u16* __restrict__ B, long sB, long ldb,
             void* __restrict__ C, long sC,
             const float* __restrict__ bias,
             const float* __restrict__ resid, long sR,
             int N, int K, float alpha)
{
  __shared__ u16 lA[128 * 64];
  __shared__ u16 lB[128 * 64];
  const int t = threadIdx.x;
  const int lane = t & 63;
  const int wid = t >> 6;

  // XCD-aware remap (grid x*y divisible by 8 for all launches here)
  const int nx = gridDim.x;
  const int bid = blockIdx.y * nx + blockIdx.x;
  const int nper = (nx * gridDim.y) >> 3;
  const int nid = (bid & 7) * nper + (bid >> 3);
  const int m0 = (nid / nx) * 128, n0 = (nid % nx) * 128;

  const long bz = blockIdx.z;
  const u16* Ab = A + bz * sA;
  const u16* Bb = B + bz * sB;

  const int row8 = t >> 3;                         // 0..31 rows per issue
  const int kc = (((t & 7) ^ ((t >> 3) & 7)) << 3);// swizzled staged chunk
  u16* ldsw = (u16*)nullptr;                       // (silence unused warnings)
  (void)ldsw; (void)lane;

  f32x4 acc[4][4];
#pragma unroll
  for (int i = 0; i < 4; ++i)
#pragma unroll
    for (int j = 0; j < 4; ++j) acc[i][j] = (f32x4){0.f, 0.f, 0.f, 0.f};

  const int ml = (t & 63) & 15, qd = (t & 63) >> 4;
  const int mlx = ml & 7;
  const int wm = (wid >> 1) * 64, wn = (wid & 1) * 64;

  for (int k0 = 0; k0 < K; k0 += 64) {
    const u16* Ap = Ab + (long)(m0 + row8) * lda + (k0 + kc);
    const u16* Bp = Bb + (long)(n0 + row8) * ldb + (k0 + kc);
    gld_lds16(Ap,            lA + wid * 512);
    gld_lds16(Ap + 32 * lda, lA + 2048 + wid * 512);
    gld_lds16(Ap + 64 * lda, lA + 4096 + wid * 512);
    gld_lds16(Ap + 96 * lda, lA + 6144 + wid * 512);
    gld_lds16(Bp,            lB + wid * 512);
    gld_lds16(Bp + 32 * ldb, lB + 2048 + wid * 512);
    gld_lds16(Bp + 64 * ldb, lB + 4096 + wid * 512);
    gld_lds16(Bp + 96 * ldb, lB + 6144 + wid * 512);
    __syncthreads();
#pragma unroll
    for (int h = 0; h < 2; ++h) {
      const int koff = (((h * 4 + qd) ^ mlx) << 3);
      bf16x8 af[4], bfr[4];
#pragma unroll
      for (int i = 0; i < 4; ++i)
        af[i] = *(const bf16x8*)&lA[(wm + i * 16 + ml) * 64 + koff];
#pragma unroll
      for (int j = 0; j < 4; ++j)
        bfr[j] = *(const bf16x8*)&lB[(wn + j * 16 + ml) * 64 + koff];
#pragma unroll
      for (int i = 0; i < 4; ++i)
#pragma unroll
        for (int j = 0; j < 4; ++j)
          acc[i][j] = __builtin_amdgcn_mfma_f32_16x16x32_bf16(af[i], bfr[j], acc[i][j], 0, 0, 0);
    }
    __syncthreads();
  }

  const long cb = bz * sC;
#pragma unroll
  for (int i = 0; i < 4; ++i) {
#pragma unroll
    for (int j = 0; j < 4; ++j) {
#pragma unroll
      for (int r = 0; r < 4; ++r) {
        int rr = m0 + wm + i * 16 + qd * 4 + r;   // C/D row = quad*4+reg (m89)
        int cc = n0 + wn + j * 16 + ml;           // C/D col = lane&15
        float v = acc[i][j][r] * alpha;
        if (BIASMODE == 1) v += bias[rr];
        if (BIASMODE == 2) v += bias[cc];
        long idx = (long)rr * N + cc;
        if (RESID) v += resid[bz * sR + idx];
        if (OUTF32) ((float*)C)[cb + idx] = v;
        else        ((u16*)C)[cb + idx] = f2b(v);
      }
    }
  }
}

// ---------------------------------------------------------------------------
// GroupNorm, f32 input [n][c][p] -> bf16 out TRANSPOSED to [n][p][c].
// ---------------------------------------------------------------------------
__global__ __launch_bounds__(256)
void groupnorm_f32(const float* __restrict__ x, const float* __restrict__ gamma,
                   const float* __restrict__ beta, u16* __restrict__ out)
{
  const int C = 512, HW = 1024;
  const int n = blockIdx.x >> 5, g = blockIdx.x & 31;
  const float* xg = x + ((long)n * C + g * 16) * HW;
  const int t = threadIdx.x;
  float s = 0.f, ss = 0.f;
  for (int ch = t; ch < 4096; ch += 256) {
    float4 u = *(const float4*)(xg + ch * 4);
    s += u.x + u.y + u.z + u.w;
    ss += u.x * u.x + u.y * u.y + u.z * u.z + u.w * u.w;
  }
#pragma unroll
  for (int off = 32; off > 0; off >>= 1) { s += __shfl_xor(s, off); ss += __shfl_xor(ss, off); }
  __shared__ float rs[4], rss[4];
  if ((t & 63) == 0) { rs[t >> 6] = s; rss[t >> 6] = ss; }
  __syncthreads();
  s  = rs[0] + rs[1] + rs[2] + rs[3];
  ss = rss[0] + rss[1] + rss[2] + rss[3];
  const float mu = s * (1.f / 16384.f);
  const float var = ss * (1.f / 16384.f) - mu * mu;
  const float rstd = rsqrtf(var + 1e-6f);
  float gm[16], bt[16];
#pragma unroll
  for (int i = 0; i < 16; ++i) {
    float ga = gamma[g * 16 + i];
    gm[i] = ga * rstd;
    bt[i] = beta[g * 16 + i] - mu * ga * rstd;
  }
  for (int p = t; p < 1024; p += 256) {
    alignas(16) u16 vals[16];
#pragma unroll
    for (int i = 0; i < 16; ++i)
      vals[i] = f2b(xg[(long)i * HW + p] * gm[i] + bt[i]);
    u16* dst = out + ((long)n * HW + p) * C + g * 16;
    *(uint4*)dst       = *(const uint4*)&vals[0];
    *(uint4*)(dst + 8) = *(const uint4*)&vals[8];
  }
}

// Same, bf16 input [n][c][p] -> bf16 out [n][p][c].
__global__ __launch_bounds__(256)
void groupnorm_bf16(const u16* __restrict__ x, const float* __restrict__ gamma,
                    const float* __restrict__ beta, u16* __restrict__ out)
{
  const int C = 512, HW = 1024;
  const int n = blockIdx.x >> 5, g = blockIdx.x & 31;
  const u16* xg = x + ((long)n * C + g * 16) * HW;
  const int t = threadIdx.x;
  float s = 0.f, ss = 0.f;
  for (int ch = t; ch < 2048; ch += 256) {
    uint4 u = *(const uint4*)(xg + ch * 8);
    uint32_t w[4] = {u.x, u.y, u.z, u.w};
#pragma unroll
    for (int k = 0; k < 4; ++k) {
      float f0 = __uint_as_float(w[k] << 16);
      float f1 = __uint_as_float(w[k] & 0xffff0000u);
      s += f0 + f1; ss += f0 * f0 + f1 * f1;
    }
  }
#pragma unroll
  for (int off = 32; off > 0; off >>= 1) { s += __shfl_xor(s, off); ss += __shfl_xor(ss, off); }
  __shared__ float rs[4], rss[4];
  if ((t & 63) == 0) { rs[t >> 6] = s; rss[t >> 6] = ss; }
  __syncthreads();
  s  = rs[0] + rs[1] + rs[2] + rs[3];
  ss = rss[0] + rss[1] + rss[2] + rss[3];
  const float mu = s * (1.f / 16384.f);
  const float var = ss * (1.f / 16384.f) - mu * mu;
  const float rstd = rsqrtf(var + 1e-6f);
  float gm[16], bt[16];
#pragma unroll
  for (int i = 0; i < 16; ++i) {
    float ga = gamma[g * 16 + i];
    gm[i] = ga * rstd;
    bt[i] = beta[g * 16 + i] - mu * ga * rstd;
  }
  for (int p = t; p < 1024; p += 256) {
    alignas(16) u16 vals[16];
#pragma unroll
    for (int i = 0; i < 16; ++i)
      vals[i] = f2b(b2f(xg[(long)i * HW + p]) * gm[i] + bt[i]);
    u16* dst = out + ((long)n * HW + p) * C + g * 16;
    *(uint4*)dst       = *(const uint4*)&vals[0];
    *(uint4*)(dst + 8) = *(const uint4*)&vals[8];
  }
}

// ---------------------------------------------------------------------------
// In-place softmax over rows of 1024 bf16. One block per row (20480 rows).
// ---------------------------------------------------------------------------
__global__ __launch_bounds__(256)
void softmax1024(u16* __restrict__ data)
{
  u16* row = data + (long)blockIdx.x * 1024;
  const int t = threadIdx.x;
  uint2 u = *(const uint2*)(row + t * 4);
  float v[4];
  v[0] = __uint_as_float(u.x << 16); v[1] = __uint_as_float(u.x & 0xffff0000u);
  v[2] = __uint_as_float(u.y << 16); v[3] = __uint_as_float(u.y & 0xffff0000u);
  float mx = fmaxf(fmaxf(v[0], v[1]), fmaxf(v[2], v[3]));
#pragma unroll
  for (int off = 32; off > 0; off >>= 1) mx = fmaxf(mx, __shfl_xor(mx, off));
  __shared__ float red[8];
  if ((t & 63) == 0) red[t >> 6] = mx;
  __syncthreads();
  mx = fmaxf(fmaxf(red[0], red[1]), fmaxf(red[2], red[3]));
  float e[4]; float s = 0.f;
#pragma unroll
  for (int k = 0; k < 4; ++k) { e[k] = __expf(v[k] - mx); s += e[k]; }
#pragma unroll
  for (int off = 32; off > 0; off >>= 1) s += __shfl_xor(s, off);
  if ((t & 63) == 0) red[4 + (t >> 6)] = s;
  __syncthreads();
  s = red[4] + red[5] + red[6] + red[7];
  float inv = 1.f / s;
  uint2 o;
  o.x = (uint32_t)f2b(e[0] * inv) | ((uint32_t)f2b(e[1] * inv) << 16);
  o.y = (uint32_t)f2b(e[2] * inv) | ((uint32_t)f2b(e[3] * inv) << 16);
  *(uint2*)(row + t * 4) = o;
}

// ---------------------------------------------------------------------------
// Temporal attention: one WAVE per pixel (b,p). qkv fused [20480][1536]
// (row = q||k||v per frame/pixel). Lane l owns channels 8l..8l+7.
// ---------------------------------------------------------------------------
__global__ __launch_bounds__(256)
void temporal_attn(const u16* __restrict__ qkv, u16* __restrict__ htp)
{
  const int t = threadIdx.x;
  const int wv = t >> 6, lane = t & 63;
  const int pix = blockIdx.x * 4 + wv;      // 0..4095 = (b, p)
  const int b = pix >> 10, p = pix & 1023;
  const long fs = 1024l * 1536;             // frame stride in qkv
  const long rowbase = ((long)b * 5 * 1024 + p) * 1536 + lane * 8;

  float qf[5][8], kf[5][8];
#pragma unroll
  for (int f = 0; f < 5; ++f) {
    bf16x8 qv = *(const bf16x8*)(qkv + rowbase + f * fs);
    bf16x8 kv = *(const bf16x8*)(qkv + rowbase + f * fs + 512);
#pragma unroll
    for (int u = 0; u < 8; ++u) { qf[f][u] = b2f((u16)qv[u]); kf[f][u] = b2f((u16)kv[u]); }
  }
  float sc[25];
#pragma unroll
  for (int i = 0; i < 5; ++i)
#pragma unroll
    for (int j = 0; j < 5; ++j) {
      float a = 0.f;
#pragma unroll
      for (int u = 0; u < 8; ++u) a += qf[i][u] * kf[j][u];
      sc[i * 5 + j] = a;
    }
#pragma unroll
  for (int m = 1; m < 64; m <<= 1)
#pragma unroll
    for (int s = 0; s < 25; ++s) sc[s] += __shfl_xor(sc[s], m);

  const float scale = 0.04419417382415922f;  // 512^-0.5
  float att[5][5];
#pragma unroll
  for (int i = 0; i < 5; ++i) {
    float m = sc[i * 5];
#pragma unroll
    for (int j = 1; j < 5; ++j) m = fmaxf(m, sc[i * 5 + j]);
    float ssum = 0.f;
#pragma unroll
    for (int j = 0; j < 5; ++j) { att[i][j] = __expf((sc[i * 5 + j] - m) * scale); ssum += att[i][j]; }
    float inv = 1.f / ssum;
#pragma unroll
    for (int j = 0; j < 5; ++j) att[i][j] *= inv;
  }

  float of[5][8];
#pragma unroll
  for (int i = 0; i < 5; ++i)
#pragma unroll
    for (int u = 0; u < 8; ++u) of[i][u] = 0.f;
#pragma unroll
  for (int s = 0; s < 5; ++s) {
    bf16x8 vvv = *(const bf16x8*)(qkv + rowbase + s * fs + 1024);
#pragma unroll
    for (int u = 0; u < 8; ++u) {
      float vf = b2f((u16)vvv[u]);
#pragma unroll
      for (int i = 0; i < 5; ++i) of[i][u] += att[i][s] * vf;
    }
  }
  const long obase = ((long)b * 5 * 1024 + p) * 512 + lane * 8;
#pragma unroll
  for (int i = 0; i < 5; ++i) {
    alignas(16) u16 ob[8];
#pragma unroll
    for (int u = 0; u < 8; ++u) ob[u] = f2b(of[i][u]);
    *(uint4*)(htp + obase + i * 1024 * 512) = *(const uint4*)ob;
  }
}

// ---------------------------------------------------------------------------
extern "C" void kernel_launch(void* const* d_in, const int* in_sizes, int n_in,
                              void* d_out, int out_size, void* d_ws, size_t ws_size,
                              hipStream_t stream)
{
  const float* x   = (const float*)d_in[0];
  const float* wq  = (const float*)d_in[1];
  const float* bq  = (const float*)d_in[2];
  const float* wk  = (const float*)d_in[3];
  const float* bk  = (const float*)d_in[4];
  const float* wv  = (const float*)d_in[5];
  const float* bv  = (const float*)d_in[6];
  const float* wo  = (const float*)d_in[7];
  const float* bo  = (const float*)d_in[8];
  const float* wqt = (const float*)d_in[9];
  const float* bqt = (const float*)d_in[10];
  const float* wkt = (const float*)d_in[11];
  const float* bkt = (const float*)d_in[12];
  const float* wvt = (const float*)d_in[13];
  const float* bvt = (const float*)d_in[14];
  const float* wot = (const float*)d_in[15];
  const float* bot = (const float*)d_in[16];
  const float* gs  = (const float*)d_in[17];
  const float* bs  = (const float*)d_in[18];
  const float* gt  = (const float*)d_in[19];
  const float* btt = (const float*)d_in[20];

  // ws = 256 MiB. Slots W0..W7 (8 x 20 MB), weights Wt (4 MB), biases Bf.
  const long U = 20l * 1024 * 512;          // elements per slot
  u16* W0 = (u16*)d_ws;
  u16* W1 = W0 + U;                          // W1..W3 contiguous 60 MB (qkv_t)
  u16* W3 = W0 + 3 * U;
  u16* W4 = W0 + 4 * U;                      // W4..W5 contiguous 40 MB (scores)
  u16* W6 = W0 + 6 * U;
  u16* W7 = W0 + 7 * U;
  u16* Wt = W0 + 8 * U;                      // 8 x 262144 bf16 weights
  float* Bf = (float*)(Wt + 8 * 262144);     // 8 x 512 f32 biases
  u16* wv_b  = Wt + 2 * 262144;
  u16* wo_b  = Wt + 3 * 262144;
  u16* wqt_b = Wt + 4 * 262144;
  u16* wot_b = Wt + 7 * 262144;

  const long S  = 524288;                   // 1024*512 per-image stride
  const long S2 = 1048576;                  // 1024*1024 per-image stride
  const float scale = 0.04419417382415922f; // 512^-0.5
  dim3 blk(256);

  setup_wb<<<1032, blk, 0, stream>>>(wq, wk, wv, wo, wqt, wkt, wvt, wot,
                                     bq, bk, bv, bo, bqt, bkt, bvt, bot, Wt, Bf);

  // hn = GroupNorm_s(x) -> W0 [n][p][c] (= [20480][512] row-major)
  groupnorm_f32<<<640, blk, 0, stream>>>(x, gs, bs, W0);
  // qk fused: M=20480, N=1024 (wq||wk), K=512 -> W1W2 [20480][1024]
  gemm_bt<0, 2, 0><<<dim3(8, 160, 1), blk, 0, stream>>>(
      W0, 0, 512, Wt, 0, 512, W1, 0, Bf, nullptr, 0, 1024, 512, 1.f);
  // v: batched z=20, M=o(512), N=p(1024): A=wv_b, Bt=hn -> W3 [20][c][p]
  gemm_bt<0, 1, 0><<<dim3(8, 4, 20), blk, 0, stream>>>(
      wv_b, 0, 512, W0, S, 512, W3, S, Bf + 1024, nullptr, 0, 1024, 512, 1.f);
  // scores = scale * q.k^T: z=20, A=q (W1, ld 1024), Bt=k (W1+512) -> W4W5
  gemm_bt<0, 0, 0><<<dim3(8, 8, 20), blk, 0, stream>>>(
      W1, S2, 1024, W1 + 512, S2, 1024, W4, S2, nullptr, nullptr, 0, 1024, 512, scale);
  softmax1024<<<20480, blk, 0, stream>>>(W4);
  // hsp^T = att . v^T: z=20, M=pq, N=c(512), K=pk(1024) -> W0 [p][c] (hn dead)
  gemm_bt<0, 0, 0><<<dim3(4, 8, 20), blk, 0, stream>>>(
      W4, S2, 1024, W3, S, 1024, W0, S, nullptr, nullptr, 0, 512, 1024, 1.f);
  // spatio = x + wo.hsp + bo: z=20 -> W6 [c][p] bf16
  gemm_bt<0, 1, 1><<<dim3(8, 4, 20), blk, 0, stream>>>(
      wo_b, 0, 512, W0, S, 512, W6, S, Bf + 1536, x, S, 1024, 512, 1.f);
  // hn_t = GroupNorm_t(spatio) -> W7 [n][p][c]
  groupnorm_bf16<<<640, blk, 0, stream>>>(W6, gt, btt, W7);
  // qkv_t fused: M=20480, N=1536 (wqt||wkt||wvt), K=512 -> W1..W3 [20480][1536]
  gemm_bt<0, 2, 0><<<dim3(12, 160, 1), blk, 0, stream>>>(
      W7, 0, 512, wqt_b, 0, 512, W1, 0, Bf + 2048, nullptr, 0, 1536, 512, 1.f);
  // per-pixel 5x5 temporal attention -> W0 htp [20480][512]
  temporal_attn<<<1024, blk, 0, stream>>>(W1, W0);
  // out = x + wot.htp + bot -> d_out f32, z=20
  gemm_bt<1, 1, 1><<<dim3(8, 4, 20), blk, 0, stream>>>(
      wot_b, 0, 512, W0, S, 512, (float*)d_out, S, Bf + 3584, x, S, 1024, 512, 1.f);
}

// Round 9
// 446.561 us; speedup vs baseline: 1.3224x; 1.0015x over previous
//
#include <hip/hip_runtime.h>
#include <hip/hip_bf16.h>
#include <stdint.h>

typedef unsigned short u16;
typedef __attribute__((ext_vector_type(8))) short bf16x8;
typedef __attribute__((ext_vector_type(4))) float f32x4;

#define DI __device__ __forceinline__

DI float b2f(u16 u) { return __uint_as_float(((uint32_t)u) << 16); }
DI u16 f2b(float f) {
  uint32_t u = __float_as_uint(f);
  u += 0x7fff + ((u >> 16) & 1);   // RNE
  return (u16)(u >> 16);
}

DI void gld_lds16(const u16* g, u16* l) {
  __builtin_amdgcn_global_load_lds((const __attribute__((address_space(1))) void*)g,
                                   (__attribute__((address_space(3))) void*)l,
                                   16, 0, 0);
}

// ---------------------------------------------------------------------------
// Setup: convert 8 weight matrices (512x512 f32) to bf16 + pack 8 biases.
// ---------------------------------------------------------------------------
__global__ __launch_bounds__(256)
void setup_wb(const float* __restrict__ w0, const float* __restrict__ w1,
              const float* __restrict__ w2, const float* __restrict__ w3,
              const float* __restrict__ w4, const float* __restrict__ w5,
              const float* __restrict__ w6, const float* __restrict__ w7,
              const float* __restrict__ b0, const float* __restrict__ b1,
              const float* __restrict__ b2, const float* __restrict__ b3,
              const float* __restrict__ b4, const float* __restrict__ b5,
              const float* __restrict__ b6, const float* __restrict__ b7,
              u16* __restrict__ dst, float* __restrict__ bdst)
{
  if (blockIdx.x >= 1024) {
    const float* bs[8] = {b0, b1, b2, b3, b4, b5, b6, b7};
    const int a = blockIdx.x - 1024;
    const int i = threadIdx.x;
    bdst[a * 512 + i] = bs[a][i];
    bdst[a * 512 + i + 256] = bs[a][i + 256];
    return;
  }
  const float* srcs[8] = {w0, w1, w2, w3, w4, w5, w6, w7};
  const int mat = blockIdx.x >> 7;
  const int i = (((blockIdx.x & 127) << 8) + threadIdx.x) * 8;
  const float* s = srcs[mat];
  float4 a = *(const float4*)(s + i);
  float4 b = *(const float4*)(s + i + 4);
  alignas(16) u16 v[8] = {f2b(a.x), f2b(a.y), f2b(a.z), f2b(a.w),
                          f2b(b.x), f2b(b.y), f2b(b.z), f2b(b.w)};
  *(uint4*)(dst + (long)mat * 262144 + i) = *(const uint4*)v;
}

// ---------------------------------------------------------------------------
// Batched GEMM: out[m][n] = alpha * sum_k A[m*lda+k]*Bt[n*ldb+k]  (+bias,+resid)
// BM=BN=128, BK=32, 256 threads (4 waves as 2x2 of 64x64), 16x16x32 bf16 MFMA.
// - XCD-aware block remap (R8: FETCH 86->26 MB on the mega-GEMMs).
// - XOR-swizzled LDS chunks (R7: SQ_LDS_BANK_CONFLICT 3.9M -> 0).
// - NEW: explicit LDS double-buffer. Prefetch for iter i+1 issues AFTER the
//   barrier of iter i, overlapping the MFMA phase; the next barrier's
//   vmcnt(0) drain sees loads that are already ~100+ cycles in flight.
// BIASMODE: 0 none, 1 bias[row], 2 bias[col].
// ---------------------------------------------------------------------------
template<int OUTF32, int BIASMODE, int RESID>
__global__ __launch_bounds__(256)
void gemm_bt(const u16* __restrict__ A, long sA, long lda,
             const u16* __restrict__ B, long sB, long ldb,
             void* __restrict__ C, long sC,
             const float* __restrict__ bias,
             const float* __restrict__ resid, long sR,
             int N, int K, float alpha)
{
  __shared__ u16 lA[2 * 128 * 32];
  __shared__ u16 lB[2 * 128 * 32];
  const int t = threadIdx.x;
  const int lane = t & 63;
  const int wid = t >> 6;

  // XCD-aware remap (grid x*y divisible by 8 for all launches here)
  const int nx = gridDim.x;
  const int bid = blockIdx.y * nx + blockIdx.x;
  const int nper = (nx * gridDim.y) >> 3;
  const int nid = (bid & 7) * nper + (bid >> 3);
  const int m0 = (nid / nx) * 128, n0 = (nid % nx) * 128;

  const long bz = blockIdx.z;
  const u16* Ab = A + bz * sA;
  const u16* Bb = B + bz * sB;

  const int row = t >> 2;                              // 0..63
  const int kc  = (((t & 3) ^ ((t >> 3) & 3)) << 3);   // swizzled staged chunk

  f32x4 acc[4][4];
#pragma unroll
  for (int i = 0; i < 4; ++i)
#pragma unroll
    for (int j = 0; j < 4; ++j) acc[i][j] = (f32x4){0.f, 0.f, 0.f, 0.f};

  const int ml = lane & 15, qd = lane >> 4;
  const int koff = ((qd ^ ((ml >> 1) & 3)) << 3);      // swizzled read offset
  const int wm = (wid >> 1) * 64, wn = (wid & 1) * 64;

  auto stage = [&](int bsel, int k0) {
    const u16* Ap = Ab + (long)(m0 + row) * lda + (k0 + kc);
    const u16* Bp = Bb + (long)(n0 + row) * ldb + (k0 + kc);
    u16* la = lA + bsel * 4096 + wid * 512;
    u16* lb = lB + bsel * 4096 + wid * 512;
    gld_lds16(Ap, la);
    gld_lds16(Ap + 64 * lda, la + 2048);
    gld_lds16(Bp, lb);
    gld_lds16(Bp + 64 * ldb, lb + 2048);
  };

  const int niter = K >> 5;
  stage(0, 0);
  for (int i = 0; i < niter; ++i) {
    __syncthreads();                       // drains buf[i&1] prefetch
    if (i + 1 < niter) stage((i + 1) & 1, (i + 1) << 5);  // overlaps MFMA below
    const u16* la = lA + (i & 1) * 4096;
    const u16* lb = lB + (i & 1) * 4096;
    bf16x8 af[4], bfr[4];
#pragma unroll
    for (int x = 0; x < 4; ++x)
      af[x] = *(const bf16x8*)&la[(wm + x * 16 + ml) * 32 + koff];
#pragma unroll
    for (int y = 0; y < 4; ++y)
      bfr[y] = *(const bf16x8*)&lb[(wn + y * 16 + ml) * 32 + koff];
#pragma unroll
    for (int x = 0; x < 4; ++x)
#pragma unroll
      for (int y = 0; y < 4; ++y)
        acc[x][y] = __builtin_amdgcn_mfma_f32_16x16x32_bf16(af[x], bfr[y], acc[x][y], 0, 0, 0);
  }

  const long cb = bz * sC;
#pragma unroll
  for (int i = 0; i < 4; ++i) {
#pragma unroll
    for (int j = 0; j < 4; ++j) {
#pragma unroll
      for (int r = 0; r < 4; ++r) {
        int rr = m0 + wm + i * 16 + qd * 4 + r;   // C/D row = quad*4+reg (m89)
        int cc = n0 + wn + j * 16 + ml;           // C/D col = lane&15
        float v = acc[i][j][r] * alpha;
        if (BIASMODE == 1) v += bias[rr];
        if (BIASMODE == 2) v += bias[cc];
        long idx = (long)rr * N + cc;
        if (RESID) v += resid[bz * sR + idx];
        if (OUTF32) ((float*)C)[cb + idx] = v;
        else        ((u16*)C)[cb + idx] = f2b(v);
      }
    }
  }
}

// ---------------------------------------------------------------------------
// GroupNorm, f32 input [n][c][p] -> bf16 out TRANSPOSED to [n][p][c].
// ---------------------------------------------------------------------------
__global__ __launch_bounds__(256)
void groupnorm_f32(const float* __restrict__ x, const float* __restrict__ gamma,
                   const float* __restrict__ beta, u16* __restrict__ out)
{
  const int C = 512, HW = 1024;
  const int n = blockIdx.x >> 5, g = blockIdx.x & 31;
  const float* xg = x + ((long)n * C + g * 16) * HW;
  const int t = threadIdx.x;
  float s = 0.f, ss = 0.f;
  for (int ch = t; ch < 4096; ch += 256) {
    float4 u = *(const float4*)(xg + ch * 4);
    s += u.x + u.y + u.z + u.w;
    ss += u.x * u.x + u.y * u.y + u.z * u.z + u.w * u.w;
  }
#pragma unroll
  for (int off = 32; off > 0; off >>= 1) { s += __shfl_xor(s, off); ss += __shfl_xor(ss, off); }
  __shared__ float rs[4], rss[4];
  if ((t & 63) == 0) { rs[t >> 6] = s; rss[t >> 6] = ss; }
  __syncthreads();
  s  = rs[0] + rs[1] + rs[2] + rs[3];
  ss = rss[0] + rss[1] + rss[2] + rss[3];
  const float mu = s * (1.f / 16384.f);
  const float var = ss * (1.f / 16384.f) - mu * mu;
  const float rstd = rsqrtf(var + 1e-6f);
  float gm[16], bt[16];
#pragma unroll
  for (int i = 0; i < 16; ++i) {
    float ga = gamma[g * 16 + i];
    gm[i] = ga * rstd;
    bt[i] = beta[g * 16 + i] - mu * ga * rstd;
  }
  for (int p = t; p < 1024; p += 256) {
    alignas(16) u16 vals[16];
#pragma unroll
    for (int i = 0; i < 16; ++i)
      vals[i] = f2b(xg[(long)i * HW + p] * gm[i] + bt[i]);
    u16* dst = out + ((long)n * HW + p) * C + g * 16;
    *(uint4*)dst       = *(const uint4*)&vals[0];
    *(uint4*)(dst + 8) = *(const uint4*)&vals[8];
  }
}

// Same, bf16 input [n][c][p] -> bf16 out [n][p][c].
__global__ __launch_bounds__(256)
void groupnorm_bf16(const u16* __restrict__ x, const float* __restrict__ gamma,
                    const float* __restrict__ beta, u16* __restrict__ out)
{
  const int C = 512, HW = 1024;
  const int n = blockIdx.x >> 5, g = blockIdx.x & 31;
  const u16* xg = x + ((long)n * C + g * 16) * HW;
  const int t = threadIdx.x;
  float s = 0.f, ss = 0.f;
  for (int ch = t; ch < 2048; ch += 256) {
    uint4 u = *(const uint4*)(xg + ch * 8);
    uint32_t w[4] = {u.x, u.y, u.z, u.w};
#pragma unroll
    for (int k = 0; k < 4; ++k) {
      float f0 = __uint_as_float(w[k] << 16);
      float f1 = __uint_as_float(w[k] & 0xffff0000u);
      s += f0 + f1; ss += f0 * f0 + f1 * f1;
    }
  }
#pragma unroll
  for (int off = 32; off > 0; off >>= 1) { s += __shfl_xor(s, off); ss += __shfl_xor(ss, off); }
  __shared__ float rs[4], rss[4];
  if ((t & 63) == 0) { rs[t >> 6] = s; rss[t >> 6] = ss; }
  __syncthreads();
  s  = rs[0] + rs[1] + rs[2] + rs[3];
  ss = rss[0] + rss[1] + rss[2] + rss[3];
  const float mu = s * (1.f / 16384.f);
  const float var = ss * (1.f / 16384.f) - mu * mu;
  const float rstd = rsqrtf(var + 1e-6f);
  float gm[16], bt[16];
#pragma unroll
  for (int i = 0; i < 16; ++i) {
    float ga = gamma[g * 16 + i];
    gm[i] = ga * rstd;
    bt[i] = beta[g * 16 + i] - mu * ga * rstd;
  }
  for (int p = t; p < 1024; p += 256) {
    alignas(16) u16 vals[16];
#pragma unroll
    for (int i = 0; i < 16; ++i)
      vals[i] = f2b(b2f(xg[(long)i * HW + p]) * gm[i] + bt[i]);
    u16* dst = out + ((long)n * HW + p) * C + g * 16;
    *(uint4*)dst       = *(const uint4*)&vals[0];
    *(uint4*)(dst + 8) = *(const uint4*)&vals[8];
  }
}

// ---------------------------------------------------------------------------
// In-place softmax over rows of 1024 bf16. One block per row (20480 rows).
// ---------------------------------------------------------------------------
__global__ __launch_bounds__(256)
void softmax1024(u16* __restrict__ data)
{
  u16* row = data + (long)blockIdx.x * 1024;
  const int t = threadIdx.x;
  uint2 u = *(const uint2*)(row + t * 4);
  float v[4];
  v[0] = __uint_as_float(u.x << 16); v[1] = __uint_as_float(u.x & 0xffff0000u);
  v[2] = __uint_as_float(u.y << 16); v[3] = __uint_as_float(u.y & 0xffff0000u);
  float mx = fmaxf(fmaxf(v[0], v[1]), fmaxf(v[2], v[3]));
#pragma unroll
  for (int off = 32; off > 0; off >>= 1) mx = fmaxf(mx, __shfl_xor(mx, off));
  __shared__ float red[8];
  if ((t & 63) == 0) red[t >> 6] = mx;
  __syncthreads();
  mx = fmaxf(fmaxf(red[0], red[1]), fmaxf(red[2], red[3]));
  float e[4]; float s = 0.f;
#pragma unroll
  for (int k = 0; k < 4; ++k) { e[k] = __expf(v[k] - mx); s += e[k]; }
#pragma unroll
  for (int off = 32; off > 0; off >>= 1) s += __shfl_xor(s, off);
  if ((t & 63) == 0) red[4 + (t >> 6)] = s;
  __syncthreads();
  s = red[4] + red[5] + red[6] + red[7];
  float inv = 1.f / s;
  uint2 o;
  o.x = (uint32_t)f2b(e[0] * inv) | ((uint32_t)f2b(e[1] * inv) << 16);
  o.y = (uint32_t)f2b(e[2] * inv) | ((uint32_t)f2b(e[3] * inv) << 16);
  *(uint2*)(row + t * 4) = o;
}

// ---------------------------------------------------------------------------
// Temporal attention: one WAVE per pixel (b,p). qkv fused [20480][1536]
// (row = q||k||v per frame/pixel). Lane l owns channels 8l..8l+7.
// ---------------------------------------------------------------------------
__global__ __launch_bounds__(256)
void temporal_attn(const u16* __restrict__ qkv, u16* __restrict__ htp)
{
  const int t = threadIdx.x;
  const int wv = t >> 6, lane = t & 63;
  const int pix = blockIdx.x * 4 + wv;      // 0..4095 = (b, p)
  const int b = pix >> 10, p = pix & 1023;
  const long fs = 1024l * 1536;             // frame stride in qkv
  const long rowbase = ((long)b * 5 * 1024 + p) * 1536 + lane * 8;

  float qf[5][8], kf[5][8];
#pragma unroll
  for (int f = 0; f < 5; ++f) {
    bf16x8 qv = *(const bf16x8*)(qkv + rowbase + f * fs);
    bf16x8 kv = *(const bf16x8*)(qkv + rowbase + f * fs + 512);
#pragma unroll
    for (int u = 0; u < 8; ++u) { qf[f][u] = b2f((u16)qv[u]); kf[f][u] = b2f((u16)kv[u]); }
  }
  float sc[25];
#pragma unroll
  for (int i = 0; i < 5; ++i)
#pragma unroll
    for (int j = 0; j < 5; ++j) {
      float a = 0.f;
#pragma unroll
      for (int u = 0; u < 8; ++u) a += qf[i][u] * kf[j][u];
      sc[i * 5 + j] = a;
    }
#pragma unroll
  for (int m = 1; m < 64; m <<= 1)
#pragma unroll
    for (int s = 0; s < 25; ++s) sc[s] += __shfl_xor(sc[s], m);

  const float scale = 0.04419417382415922f;  // 512^-0.5
  float att[5][5];
#pragma unroll
  for (int i = 0; i < 5; ++i) {
    float m = sc[i * 5];
#pragma unroll
    for (int j = 1; j < 5; ++j) m = fmaxf(m, sc[i * 5 + j]);
    float ssum = 0.f;
#pragma unroll
    for (int j = 0; j < 5; ++j) { att[i][j] = __expf((sc[i * 5 + j] - m) * scale); ssum += att[i][j]; }
    float inv = 1.f / ssum;
#pragma unroll
    for (int j = 0; j < 5; ++j) att[i][j] *= inv;
  }

  float of[5][8];
#pragma unroll
  for (int i = 0; i < 5; ++i)
#pragma unroll
    for (int u = 0; u < 8; ++u) of[i][u] = 0.f;
#pragma unroll
  for (int s = 0; s < 5; ++s) {
    bf16x8 vvv = *(const bf16x8*)(qkv + rowbase + s * fs + 1024);
#pragma unroll
    for (int u = 0; u < 8; ++u) {
      float vf = b2f((u16)vvv[u]);
#pragma unroll
      for (int i = 0; i < 5; ++i) of[i][u] += att[i][s] * vf;
    }
  }
  const long obase = ((long)b * 5 * 1024 + p) * 512 + lane * 8;
#pragma unroll
  for (int i = 0; i < 5; ++i) {
    alignas(16) u16 ob[8];
#pragma unroll
    for (int u = 0; u < 8; ++u) ob[u] = f2b(of[i][u]);
    *(uint4*)(htp + obase + i * 1024 * 512) = *(const uint4*)ob;
  }
}

// ---------------------------------------------------------------------------
extern "C" void kernel_launch(void* const* d_in, const int* in_sizes, int n_in,
                              void* d_out, int out_size, void* d_ws, size_t ws_size,
                              hipStream_t stream)
{
  const float* x   = (const float*)d_in[0];
  const float* wq  = (const float*)d_in[1];
  const float* bq  = (const float*)d_in[2];
  const float* wk  = (const float*)d_in[3];
  const float* bk  = (const float*)d_in[4];
  const float* wv  = (const float*)d_in[5];
  const float* bv  = (const float*)d_in[6];
  const float* wo  = (const float*)d_in[7];
  const float* bo  = (const float*)d_in[8];
  const float* wqt = (const float*)d_in[9];
  const float* bqt = (const float*)d_in[10];
  const float* wkt = (const float*)d_in[11];
  const float* bkt = (const float*)d_in[12];
  const float* wvt = (const float*)d_in[13];
  const float* bvt = (const float*)d_in[14];
  const float* wot = (const float*)d_in[15];
  const float* bot = (const float*)d_in[16];
  const float* gs  = (const float*)d_in[17];
  const float* bs  = (const float*)d_in[18];
  const float* gt  = (const float*)d_in[19];
  const float* btt = (const float*)d_in[20];

  // ws = 256 MiB. Slots W0..W7 (8 x 20 MB), weights Wt (4 MB), biases Bf.
  const long U = 20l * 1024 * 512;          // elements per slot
  u16* W0 = (u16*)d_ws;
  u16* W1 = W0 + U;                          // W1..W3 contiguous 60 MB (qkv_t)
  u16* W3 = W0 + 3 * U;
  u16* W4 = W0 + 4 * U;                      // W4..W5 contiguous 40 MB (scores)
  u16* W6 = W0 + 6 * U;
  u16* W7 = W0 + 7 * U;
  u16* Wt = W0 + 8 * U;                      // 8 x 262144 bf16 weights
  float* Bf = (float*)(Wt + 8 * 262144);     // 8 x 512 f32 biases
  u16* wv_b  = Wt + 2 * 262144;
  u16* wo_b  = Wt + 3 * 262144;
  u16* wqt_b = Wt + 4 * 262144;
  u16* wot_b = Wt + 7 * 262144;

  const long S  = 524288;                   // 1024*512 per-image stride
  const long S2 = 1048576;                  // 1024*1024 per-image stride
  const float scale = 0.04419417382415922f; // 512^-0.5
  dim3 blk(256);

  setup_wb<<<1032, blk, 0, stream>>>(wq, wk, wv, wo, wqt, wkt, wvt, wot,
                                     bq, bk, bv, bo, bqt, bkt, bvt, bot, Wt, Bf);

  // hn = GroupNorm_s(x) -> W0 [n][p][c] (= [20480][512] row-major)
  groupnorm_f32<<<640, blk, 0, stream>>>(x, gs, bs, W0);
  // qk fused: M=20480, N=1024 (wq||wk), K=512 -> W1W2 [20480][1024]
  gemm_bt<0, 2, 0><<<dim3(8, 160, 1), blk, 0, stream>>>(
      W0, 0, 512, Wt, 0, 512, W1, 0, Bf, nullptr, 0, 1024, 512, 1.f);
  // v: batched z=20, M=o(512), N=p(1024): A=wv_b, Bt=hn -> W3 [20][c][p]
  gemm_bt<0, 1, 0><<<dim3(8, 4, 20), blk, 0, stream>>>(
      wv_b, 0, 512, W0, S, 512, W3, S, Bf + 1024, nullptr, 0, 1024, 512, 1.f);
  // scores = scale * q.k^T: z=20, A=q (W1, ld 1024), Bt=k (W1+512) -> W4W5
  gemm_bt<0, 0, 0><<<dim3(8, 8, 20), blk, 0, stream>>>(
      W1, S2, 1024, W1 + 512, S2, 1024, W4, S2, nullptr, nullptr, 0, 1024, 512, scale);
  softmax1024<<<20480, blk, 0, stream>>>(W4);
  // hsp^T = att . v^T: z=20, M=pq, N=c(512), K=pk(1024) -> W0 [p][c] (hn dead)
  gemm_bt<0, 0, 0><<<dim3(4, 8, 20), blk, 0, stream>>>(
      W4, S2, 1024, W3, S, 1024, W0, S, nullptr, nullptr, 0, 512, 1024, 1.f);
  // spatio = x + wo.hsp + bo: z=20 -> W6 [c][p] bf16
  gemm_bt<0, 1, 1><<<dim3(8, 4, 20), blk, 0, stream>>>(
      wo_b, 0, 512, W0, S, 512, W6, S, Bf + 1536, x, S, 1024, 512, 1.f);
  // hn_t = GroupNorm_t(spatio) -> W7 [n][p][c]
  groupnorm_bf16<<<640, blk, 0, stream>>>(W6, gt, btt, W7);
  // qkv_t fused: M=20480, N=1536 (wqt||wkt||wvt), K=512 -> W1..W3 [20480][1536]
  gemm_bt<0, 2, 0><<<dim3(12, 160, 1), blk, 0, stream>>>(
      W7, 0, 512, wqt_b, 0, 512, W1, 0, Bf + 2048, nullptr, 0, 1536, 512, 1.f);
  // per-pixel 5x5 temporal attention -> W0 htp [20480][512]
  temporal_attn<<<1024, blk, 0, stream>>>(W1, W0);
  // out = x + wot.htp + bot -> d_out f32, z=20
  gemm_bt<1, 1, 1><<<dim3(8, 4, 20), blk, 0, stream>>>(
      wot_b, 0, 512, W0, S, 512, (float*)d_out, S, Bf + 3584, x, S, 1024, 512, 1.f);
}